// Round 1
// baseline (1381.322 us; speedup 1.0000x reference)
//
#include <hip/hip_runtime.h>
#include <math.h>

#define NN 325
#define FD 64
#define KH 4
#define DH 16
#define BT 192
#define NN2 (NN*NN)
#define PST (NN*DH)   // 5200 floats per (proj, head, bt) slice

__device__ inline float wred_max(float v){
  #pragma unroll
  for (int o = 32; o; o >>= 1) v = fmaxf(v, __shfl_xor(v, o, 64));
  return v;
}
__device__ inline float wred_sum(float v){
  #pragma unroll
  for (int o = 32; o; o >>= 1) v += __shfl_xor(v, o, 64);
  return v;
}

// ---------------- bias: [4][N][N] = sum_k W[h,k,n,m] * A[k,n,m] ----------------
__global__ __launch_bounds__(256) void bias_kernel(
    const float* __restrict__ Wdi, const float* __restrict__ Wdo,
    const float* __restrict__ A,   const float* __restrict__ AT,
    float* __restrict__ bias){
  int idx = blockIdx.x * 256 + threadIdx.x;
  if (idx >= KH * NN2) return;
  int h = idx / NN2, r = idx - h * NN2;
  float s = 0.f;
  if (h < 2){
    #pragma unroll
    for (int k = 0; k < 3; ++k) s += Wdi[(h*3 + k)*NN2 + r] * A[k*NN2 + r];
  } else {
    int h2 = h - 2;
    #pragma unroll
    for (int k = 0; k < 3; ++k) s += Wdo[(h2*3 + k)*NN2 + r] * AT[k*NN2 + r];
  }
  bias[idx] = s;
}

// ---------------- projections: q,k,ks,v,vs ----------------
// proj layout: [p][h][bt][n][d], p in {q,k,ks,v,vs}
__global__ __launch_bounds__(256) void proj_kernel(
    const float* __restrict__ x,
    const float* __restrict__ Wq,  const float* __restrict__ bq,
    const float* __restrict__ Wk,  const float* __restrict__ bk,
    const float* __restrict__ Wks, const float* __restrict__ bks,
    const float* __restrict__ Wv,  const float* __restrict__ bv,
    const float* __restrict__ Wvs, const float* __restrict__ bvs,
    float* __restrict__ proj){
  __shared__ float4 xs4[256];   // 16 rows x 64 feat
  int tid = threadIdx.x;
  xs4[tid] = ((const float4*)x)[blockIdx.x * 256 + tid];
  __syncthreads();
  const float* Ws[5] = {Wq, Wk, Wks, Wv, Wvs};
  const float* bs[5] = {bq, bk, bks, bv, bvs};
  int r = tid >> 4, d = tid & 15;
  int row = blockIdx.x * 16 + r;
  int bt = row / NN;
  int n  = row - bt * NN;
  const float4* xr = &xs4[r * 16];
  #pragma unroll
  for (int p = 0; p < 5; ++p){
    #pragma unroll
    for (int h = 0; h < KH; ++h){
      int f = h * 16 + d;
      const float4* wr = (const float4*)(Ws[p] + f * 64);
      float acc = bs[p][f];
      #pragma unroll
      for (int c = 0; c < 16; ++c){
        float4 w = wr[c], xx = xr[c];
        acc += xx.x*w.x + xx.y*w.y + xx.z*w.z + xx.w*w.w;
      }
      proj[((p*KH + h)*BT + bt)*PST + n*16 + d] = acc;
    }
  }
}

// ---------------- attention ----------------
// grid: (4 row tiles, BT, KH); block 256 = 4 waves; one wave per query row.
__global__ __launch_bounds__(256) void attn_kernel(
    const float* __restrict__ proj, const float* __restrict__ bias,
    float* __restrict__ val){
  __shared__ float k_lds[NN * 17];   // stride-17 pad: kills 32-way bank conflict
  __shared__ float v_lds[NN * 17];
  __shared__ float e_buf[4][336];    // per-wave score row (same-lane RAW only)
  int h = blockIdx.z, bt = blockIdx.y;
  int tid = threadIdx.x, lane = tid & 63, wid = tid >> 6;
  const float* qb  = proj + ((0*KH + h)*BT + bt)*PST;
  const float* kb  = proj + ((1*KH + h)*BT + bt)*PST;
  const float* ksb = proj + ((2*KH + h)*BT + bt)*PST;
  const float* vb  = proj + ((3*KH + h)*BT + bt)*PST;
  const float* vsb = proj + ((4*KH + h)*BT + bt)*PST;

  for (int i = tid; i < PST/4; i += 256){
    float4 kw = ((const float4*)kb)[i];
    float4 vw = ((const float4*)vb)[i];
    int m = i >> 2, db = (i & 3) * 4;
    float* kp = &k_lds[m*17 + db];
    kp[0]=kw.x; kp[1]=kw.y; kp[2]=kw.z; kp[3]=kw.w;
    float* vp = &v_lds[m*17 + db];
    vp[0]=vw.x; vp[1]=vw.y; vp[2]=vw.z; vp[3]=vw.w;
  }
  __syncthreads();

  int start = blockIdx.x * 82;
  int end = min(start + 82, NN);
  const float scale = 0.25f; // 1/sqrt(16)

  for (int n = start + wid; n < end; n += 4){
    float qd[16];
    {
      const float4* q4 = (const float4*)(qb + n*16);
      float4 a0=q4[0], a1=q4[1], a2=q4[2], a3=q4[3];
      qd[0]=a0.x; qd[1]=a0.y; qd[2]=a0.z; qd[3]=a0.w;
      qd[4]=a1.x; qd[5]=a1.y; qd[6]=a1.z; qd[7]=a1.w;
      qd[8]=a2.x; qd[9]=a2.y; qd[10]=a2.z; qd[11]=a2.w;
      qd[12]=a3.x; qd[13]=a3.y; qd[14]=a3.z; qd[15]=a3.w;
    }
    float dks;
    {
      const float4* s4 = (const float4*)(ksb + n*16);
      float4 b0=s4[0], b1=s4[1], b2=s4[2], b3=s4[3];
      dks = qd[0]*b0.x + qd[1]*b0.y + qd[2]*b0.z + qd[3]*b0.w
          + qd[4]*b1.x + qd[5]*b1.y + qd[6]*b1.z + qd[7]*b1.w
          + qd[8]*b2.x + qd[9]*b2.y + qd[10]*b2.z + qd[11]*b2.w
          + qd[12]*b3.x + qd[13]*b3.y + qd[14]*b3.z + qd[15]*b3.w;
    }
    float es = 1.f / (1.f + expf(-dks * scale));
    const float* brow = bias + h*NN2 + n*NN;
    float* eb = e_buf[wid];

    // pass 1: scores + row max
    float lmax = -3.4e38f;
    for (int m = lane; m < NN; m += 64){
      const float* kr = &k_lds[m*17];
      float e = 0.f;
      #pragma unroll
      for (int d2 = 0; d2 < 16; ++d2) e += qd[d2] * kr[d2];
      e = e * scale + brow[m];
      eb[m] = e;
      lmax = fmaxf(lmax, e);
    }
    lmax = wred_max(lmax);

    // pass 2: exp, sum, unnormalized sum(ex * v)
    float sum = 0.f;
    float acc[16];
    #pragma unroll
    for (int d2 = 0; d2 < 16; ++d2) acc[d2] = 0.f;
    for (int m = lane; m < NN; m += 64){
      float ex = expf(eb[m] - lmax);
      sum += ex;
      const float* vr = &v_lds[m*17];
      #pragma unroll
      for (int d2 = 0; d2 < 16; ++d2) acc[d2] += ex * vr[d2];
    }
    sum = wred_sum(sum);
    #pragma unroll
    for (int d2 = 0; d2 < 16; ++d2) acc[d2] = wred_sum(acc[d2]);

    float inv = 1.f / (es + sum);
    float asum = sum * inv;
    if (lane < 16){
      float myacc = 0.f;
      #pragma unroll
      for (int d2 = 0; d2 < 16; ++d2) myacc = (lane == d2) ? acc[d2] : myacc;
      float vsv = vsb[n*16 + lane];
      val[(bt*NN + n)*FD + h*16 + lane] = myacc * inv + (1.f - asum) * vsv;
    }
  }
}

// ---------------- FFN + residual + LayerNorm ----------------
// block 256 = 4 waves, 1 wave per row, lane = feature
__global__ __launch_bounds__(256) void ffn_kernel(
    const float* __restrict__ val, const float* __restrict__ x,
    const float* __restrict__ Wf1, const float* __restrict__ bf1,
    const float* __restrict__ Wf2, const float* __restrict__ bf2,
    const float* __restrict__ g_ln, const float* __restrict__ b_ln,
    float* __restrict__ out){
  __shared__ float vrow[4][64];
  __shared__ float hrow[4][64];
  int tid = threadIdx.x, lane = tid & 63, wid = tid >> 6;
  int row = blockIdx.x * 4 + wid;
  vrow[wid][lane] = val[row*64 + lane];
  __syncthreads();
  float t1 = bf1[lane];
  const float4* w1 = (const float4*)(Wf1 + lane*64);
  #pragma unroll
  for (int c = 0; c < 16; ++c){
    float4 w = w1[c];
    t1 += vrow[wid][4*c]*w.x + vrow[wid][4*c+1]*w.y
        + vrow[wid][4*c+2]*w.z + vrow[wid][4*c+3]*w.w;
  }
  float g1 = 0.5f * t1 * (1.f + erff(t1 * 0.70710678118654752f)); // exact gelu
  hrow[wid][lane] = g1;
  __syncthreads();
  float t2 = bf2[lane] + x[row*64 + lane];
  const float4* w2 = (const float4*)(Wf2 + lane*64);
  #pragma unroll
  for (int c = 0; c < 16; ++c){
    float4 w = w2[c];
    t2 += hrow[wid][4*c]*w.x + hrow[wid][4*c+1]*w.y
        + hrow[wid][4*c+2]*w.z + hrow[wid][4*c+3]*w.w;
  }
  float mu = wred_sum(t2) * (1.f/64.f);
  float dv = t2 - mu;
  float var = wred_sum(dv*dv) * (1.f/64.f);
  out[row*64 + lane] = g_ln[lane] * dv / sqrtf(var + 1e-5f) + b_ln[lane];
}

extern "C" void kernel_launch(void* const* d_in, const int* in_sizes, int n_in,
                              void* d_out, int out_size, void* d_ws, size_t ws_size,
                              hipStream_t stream) {
  const float* x    = (const float*)d_in[0];
  const float* A    = (const float*)d_in[1];
  const float* AT   = (const float*)d_in[2];
  const float* Wq   = (const float*)d_in[3];
  const float* bq   = (const float*)d_in[4];
  const float* Wk   = (const float*)d_in[5];
  const float* bk   = (const float*)d_in[6];
  const float* Wks  = (const float*)d_in[7];
  const float* bks  = (const float*)d_in[8];
  const float* Wv   = (const float*)d_in[9];
  const float* bv   = (const float*)d_in[10];
  const float* Wvs  = (const float*)d_in[11];
  const float* bvs  = (const float*)d_in[12];
  const float* Wdi  = (const float*)d_in[13];
  const float* Wdo  = (const float*)d_in[14];
  const float* Wf1  = (const float*)d_in[15];
  const float* bf1  = (const float*)d_in[16];
  const float* Wf2  = (const float*)d_in[17];
  const float* bf2  = (const float*)d_in[18];
  const float* g_ln = (const float*)d_in[19];
  const float* b_ln = (const float*)d_in[20];
  float* out = (float*)d_out;

  float* ws   = (float*)d_ws;
  float* proj = ws;                         // 5*4*192*5200 = 19,968,000 floats
  float* bias = proj + 19968000;            // 4*325*325  =    422,500 floats
  float* val  = bias + 422500;              // 62400*64   =  3,993,600 floats

  bias_kernel<<<(KH*NN2 + 255)/256, 256, 0, stream>>>(Wdi, Wdo, A, AT, bias);
  proj_kernel<<<3900, 256, 0, stream>>>(x, Wq, bq, Wk, bk, Wks, bks,
                                        Wv, bv, Wvs, bvs, proj);
  attn_kernel<<<dim3(4, BT, KH), 256, 0, stream>>>(proj, bias, val);
  ffn_kernel<<<15600, 256, 0, stream>>>(val, x, Wf1, bf1, Wf2, bf2,
                                        g_ln, b_ln, out);
}

// Round 2
// 518.241 us; speedup vs baseline: 2.6654x; 2.6654x over previous
//
#include <hip/hip_runtime.h>
#include <math.h>

#define NN 325
#define FD 64
#define KH 4
#define DH 16
#define BT 192
#define NN2 (NN*NN)
#define PST (NN*DH)     // 5200 elems per (proj,head,bt) slice
#define SSTR 340        // S row stride (dwords); P row = same bytes as bf16 (680)
#define VSTR 360        // vT row stride (bf16)

typedef __attribute__((ext_vector_type(8))) short short8;
typedef __attribute__((ext_vector_type(4))) float f32x4;

union U8 { uint4 u; short8 s; };
__device__ inline short8 lds8(const ushort* p){ U8 t; t.u = *(const uint4*)p; return t.s; }
__device__ inline float b2f(ushort v){ return __uint_as_float(((unsigned)v) << 16); }
__device__ inline ushort f2b(float f){
  unsigned u = __float_as_uint(f);
  u += 0x7fff + ((u >> 16) & 1);
  return (ushort)(u >> 16);
}

__device__ inline float wred_sum(float v){
  #pragma unroll
  for (int o = 32; o; o >>= 1) v += __shfl_xor(v, o, 64);
  return v;
}

// ---------------- x -> bf16 ----------------
__global__ __launch_bounds__(256) void cvt_kernel(const float* __restrict__ x,
                                                  ushort* __restrict__ xb, int n8){
  int i = blockIdx.x * 256 + threadIdx.x;
  if (i >= n8) return;
  const float4* xp = (const float4*)x + (size_t)i * 2;
  float4 v0 = xp[0], v1 = xp[1];
  uint4 u;
  u.x = f2b(v0.x) | ((unsigned)f2b(v0.y) << 16);
  u.y = f2b(v0.z) | ((unsigned)f2b(v0.w) << 16);
  u.z = f2b(v1.x) | ((unsigned)f2b(v1.y) << 16);
  u.w = f2b(v1.z) | ((unsigned)f2b(v1.w) << 16);
  ((uint4*)xb)[i] = u;
}

// ---------------- pack W's -> Wcat bf16 [320][64], bcat[320] ----------------
__global__ __launch_bounds__(256) void wpack_kernel(
    const float* __restrict__ Wq,  const float* __restrict__ bq,
    const float* __restrict__ Wk,  const float* __restrict__ bk,
    const float* __restrict__ Wks, const float* __restrict__ bks,
    const float* __restrict__ Wv,  const float* __restrict__ bv,
    const float* __restrict__ Wvs, const float* __restrict__ bvs,
    ushort* __restrict__ Wcat, float* __restrict__ bcat){
  const float* Ws[5] = {Wq, Wk, Wks, Wv, Wvs};
  const float* bs[5] = {bq, bk, bks, bv, bvs};
  for (int f = threadIdx.x; f < 320; f += 256){
    int p = f >> 6, fl = f & 63;
    const float* wr = Ws[p] + fl * 64;
    unsigned* dst = (unsigned*)Wcat + f * 32;
    #pragma unroll
    for (int c = 0; c < 32; ++c)
      dst[c] = f2b(wr[2*c]) | ((unsigned)f2b(wr[2*c+1]) << 16);
    bcat[f] = bs[p][fl];
  }
}

// ---------------- bias: [4][N][N] ----------------
__global__ __launch_bounds__(256) void bias_kernel(
    const float* __restrict__ Wdi, const float* __restrict__ Wdo,
    const float* __restrict__ A,   const float* __restrict__ AT,
    float* __restrict__ bias){
  int idx = blockIdx.x * 256 + threadIdx.x;
  if (idx >= KH * NN2) return;
  int h = idx / NN2, r = idx - h * NN2;
  float s = 0.f;
  if (h < 2){
    #pragma unroll
    for (int k = 0; k < 3; ++k) s += Wdi[(h*3 + k)*NN2 + r] * A[k*NN2 + r];
  } else {
    int h2 = h - 2;
    #pragma unroll
    for (int k = 0; k < 3; ++k) s += Wdo[(h2*3 + k)*NN2 + r] * AT[k*NN2 + r];
  }
  bias[idx] = s;
}

// ---------------- projections via MFMA: proj bf16 [p][h][bt][n][d] ----------------
__global__ __launch_bounds__(256) void proj_kernel(
    const ushort* __restrict__ xb, const ushort* __restrict__ Wcat,
    const float* __restrict__ bcat, ushort* __restrict__ proj){
  int tid = threadIdx.x, lane = tid & 63, wid = tid >> 6;
  int r0 = blockIdx.x * 64 + wid * 16;
  int m = lane & 15, kc = lane >> 4;     // A row, k-chunk
  short8 a0 = lds8(xb + ((size_t)(r0 + m) * 64 + kc * 8));
  short8 a1 = lds8(xb + ((size_t)(r0 + m) * 64 + kc * 8 + 32));
  int btA[4], nA[4];
  #pragma unroll
  for (int rg = 0; rg < 4; ++rg){
    int gr = r0 + kc * 4 + rg;           // C row = (lane>>4)*4 + rg
    btA[rg] = gr / NN; nA[rg] = gr - btA[rg] * NN;
  }
  for (int ct = 0; ct < 20; ++ct){
    short8 b0 = lds8(Wcat + ((size_t)(ct*16 + m) * 64 + kc * 8));
    short8 b1 = lds8(Wcat + ((size_t)(ct*16 + m) * 64 + kc * 8 + 32));
    float bv = bcat[ct*16 + m];
    f32x4 acc = {bv, bv, bv, bv};
    acc = __builtin_amdgcn_mfma_f32_16x16x32_bf16(a0, b0, acc, 0, 0, 0);
    acc = __builtin_amdgcn_mfma_f32_16x16x32_bf16(a1, b1, acc, 0, 0, 0);
    #pragma unroll
    for (int rg = 0; rg < 4; ++rg){
      size_t addr = ((size_t)ct * BT + btA[rg]) * PST + nA[rg] * 16 + m;
      proj[addr] = f2b(acc[rg]);
    }
  }
}

// ---------------- attention via MFMA ----------------
// grid (192, 4) = (bt, h); 256 threads = 4 waves = 2 wave-pairs, 2 Q-tiles in flight.
__global__ __launch_bounds__(256) void attn_kernel(
    const ushort* __restrict__ proj, const float* __restrict__ bias,
    float* __restrict__ val){
  __shared__ float  S[2][16 * SSTR];   // fp32 scores; reused in-place as bf16 P
  __shared__ ushort vT[16 * VSTR];     // transposed V
  __shared__ float  es[336];
  __shared__ float  rstat[2][16][2];   // {inv, 1-asum}
  int h = blockIdx.y, bt = blockIdx.x;
  int tid = threadIdx.x, lane = tid & 63, wid = tid >> 6;
  int slot = wid >> 1, half = wid & 1;
  const ushort* qb  = proj + (size_t)((0*4 + h)*BT + bt) * PST;
  const ushort* kb  = proj + (size_t)((1*4 + h)*BT + bt) * PST;
  const ushort* ksb = proj + (size_t)((2*4 + h)*BT + bt) * PST;
  const ushort* vb  = proj + (size_t)((3*4 + h)*BT + bt) * PST;
  const ushort* vsb = proj + (size_t)((4*4 + h)*BT + bt) * PST;

  // stage vT (transpose V), zero padding cols
  for (int i = tid; i < 2600; i += 256){
    unsigned u = ((const unsigned*)vb)[i];
    int n = (2*i) >> 4, d = (2*i) & 15;
    vT[d*VSTR + n]       = (ushort)(u & 0xffff);
    vT[(d+1)*VSTR + n]   = (ushort)(u >> 16);
  }
  for (int i = tid; i < 16*35; i += 256){
    int d = i / 35, mm = 325 + i % 35;
    vT[d*VSTR + mm] = 0;
  }
  // es = sigmoid(q . ks / 4)
  for (int n = tid; n < 336; n += 256){
    float s = 1.0f;
    if (n < 325){
      const unsigned* qp = (const unsigned*)(qb + (size_t)n * 16);
      const unsigned* kp = (const unsigned*)(ksb + (size_t)n * 16);
      float dot = 0.f;
      #pragma unroll
      for (int c = 0; c < 8; ++c){
        unsigned qv = qp[c], kv = kp[c];
        dot += b2f((ushort)(qv & 0xffff)) * b2f((ushort)(kv & 0xffff))
             + b2f((ushort)(qv >> 16))    * b2f((ushort)(kv >> 16));
      }
      s = 1.f / (1.f + expf(-dot * 0.25f));
    }
    es[n] = s;
  }
  __syncthreads();

  const float NEG = -1e30f;
  for (int t = 0; t < 11; ++t){
    int qt = t * 2 + slot;
    bool act = (qt < 21);
    // ---- S phase: S = Q K^T (raw dot), halves split col-tiles ----
    if (act){
      int m = lane & 15, kc = lane >> 4;
      short8 aq = {0,0,0,0,0,0,0,0};
      if (kc < 2)
        aq = lds8(qb + ((size_t)(qt*16 + m) * 16 + kc * 8));
      int c0 = half ? 11 : 0, c1 = half ? 21 : 11;
      for (int ct = c0; ct < c1; ++ct){
        short8 bk = {0,0,0,0,0,0,0,0};
        if (kc < 2)
          bk = lds8(kb + ((size_t)(ct*16 + m) * 16 + kc * 8));
        f32x4 acc = {0.f, 0.f, 0.f, 0.f};
        acc = __builtin_amdgcn_mfma_f32_16x16x32_bf16(aq, bk, acc, 0, 0, 0);
        float* sp = &S[slot][0];
        int col = ct*16 + m, rb = kc * 4;
        #pragma unroll
        for (int rg = 0; rg < 4; ++rg) sp[(rb + rg)*SSTR + col] = acc[rg];
      }
    }
    __syncthreads();
    // ---- softmax (rows split across halves) ----
    if (act){
      int r = half * 8 + (lane >> 3), c = lane & 7;
      int n = qt * 16 + r;
      int nb = min(n, NN - 1);
      const float* bp = bias + (size_t)h * NN2 + (size_t)nb * NN;
      float* sr = &S[slot][r * SSTR];
      float mx = NEG;
      #pragma unroll
      for (int j = 0; j < 11; ++j){
        int m0 = c * 4 + 32 * j;
        if (m0 < 336){
          float4 e4 = *(float4*)(sr + m0);
          float e0 = (m0+0 < NN) ? e4.x * 0.25f + bp[m0+0] : NEG;
          float e1 = (m0+1 < NN) ? e4.y * 0.25f + bp[m0+1] : NEG;
          float e2 = (m0+2 < NN) ? e4.z * 0.25f + bp[m0+2] : NEG;
          float e3 = (m0+3 < NN) ? e4.w * 0.25f + bp[m0+3] : NEG;
          *(float4*)(sr + m0) = make_float4(e0, e1, e2, e3);
          mx = fmaxf(mx, fmaxf(fmaxf(e0, e1), fmaxf(e2, e3)));
        }
      }
      mx = fmaxf(mx, __shfl_xor(mx, 1, 64));
      mx = fmaxf(mx, __shfl_xor(mx, 2, 64));
      mx = fmaxf(mx, __shfl_xor(mx, 4, 64));
      float sum = 0.f;
      ushort* pr = (ushort*)sr;          // P row (bf16), capacity 680
      #pragma unroll
      for (int j = 0; j < 11; ++j){
        int m0 = c * 4 + 32 * j;
        if (m0 < 336){
          float4 e4 = *(float4*)(sr + m0);
          float x0 = expf(e4.x - mx), x1 = expf(e4.y - mx);
          float x2 = expf(e4.z - mx), x3 = expf(e4.w - mx);
          ushort p0 = f2b(x0), p1 = f2b(x1), p2 = f2b(x2), p3 = f2b(x3);
          sum += b2f(p0) + b2f(p1) + b2f(p2) + b2f(p3);
          uint2 w;
          w.x = p0 | ((unsigned)p1 << 16);
          w.y = p2 | ((unsigned)p3 << 16);
          *(uint2*)(pr + m0) = w;
        } else {                          // m0 in [336,352): zero P tail
          *(uint2*)(pr + m0) = make_uint2(0u, 0u);
        }
      }
      sum += __shfl_xor(sum, 1, 64);
      sum += __shfl_xor(sum, 2, 64);
      sum += __shfl_xor(sum, 4, 64);
      float iv = 1.f / (es[n] + sum);
      if (c == 0){ rstat[slot][r][0] = iv; rstat[slot][r][1] = 1.f - sum * iv; }
    }
    __syncthreads();
    // ---- PV + epilogue (half 0 only) ----
    if (act && half == 0){
      int d = lane & 15, kc = lane >> 4;
      const ushort* prow = (const ushort*)&S[slot][0] + (size_t)d * (SSTR * 2);
      const ushort* vrow = &vT[d * VSTR];
      f32x4 acc = {0.f, 0.f, 0.f, 0.f};
      #pragma unroll
      for (int tt = 0; tt < 11; ++tt){
        short8 ap = lds8(prow + kc * 8 + 32 * tt);
        short8 bv = lds8(vrow + kc * 8 + 32 * tt);
        acc = __builtin_amdgcn_mfma_f32_16x16x32_bf16(ap, bv, acc, 0, 0, 0);
      }
      #pragma unroll
      for (int rg = 0; rg < 4; ++rg){
        int r = kc * 4 + rg, n = qt * 16 + r;
        if (n < NN){
          float iv = rstat[slot][r][0], om = rstat[slot][r][1];
          float vs = b2f(vsb[(size_t)n * 16 + d]);
          val[((size_t)bt * NN + n) * FD + h * 16 + d] = acc[rg] * iv + om * vs;
        }
      }
    }
    __syncthreads();
  }
}

// ---------------- FFN + residual + LayerNorm ----------------
__global__ __launch_bounds__(256) void ffn_kernel(
    const float* __restrict__ val, const float* __restrict__ x,
    const float* __restrict__ Wf1, const float* __restrict__ bf1,
    const float* __restrict__ Wf2, const float* __restrict__ bf2,
    const float* __restrict__ g_ln, const float* __restrict__ b_ln,
    float* __restrict__ out){
  __shared__ float vrow[4][64];
  __shared__ float hrow[4][64];
  int tid = threadIdx.x, lane = tid & 63, wid = tid >> 6;
  int row = blockIdx.x * 4 + wid;
  vrow[wid][lane] = val[(size_t)row * 64 + lane];
  __syncthreads();
  float t1 = bf1[lane];
  const float4* w1 = (const float4*)(Wf1 + lane * 64);
  #pragma unroll
  for (int c = 0; c < 16; ++c){
    float4 w = w1[c];
    t1 += vrow[wid][4*c]*w.x + vrow[wid][4*c+1]*w.y
        + vrow[wid][4*c+2]*w.z + vrow[wid][4*c+3]*w.w;
  }
  float g1 = 0.5f * t1 * (1.f + erff(t1 * 0.70710678118654752f));
  hrow[wid][lane] = g1;
  __syncthreads();
  float t2 = bf2[lane] + x[(size_t)row * 64 + lane];
  const float4* w2 = (const float4*)(Wf2 + lane * 64);
  #pragma unroll
  for (int c = 0; c < 16; ++c){
    float4 w = w2[c];
    t2 += hrow[wid][4*c]*w.x + hrow[wid][4*c+1]*w.y
        + hrow[wid][4*c+2]*w.z + hrow[wid][4*c+3]*w.w;
  }
  float mu = wred_sum(t2) * (1.f/64.f);
  float dv = t2 - mu;
  float var = wred_sum(dv*dv) * (1.f/64.f);
  out[(size_t)row * 64 + lane] = g_ln[lane] * dv / sqrtf(var + 1e-5f) + b_ln[lane];
}

extern "C" void kernel_launch(void* const* d_in, const int* in_sizes, int n_in,
                              void* d_out, int out_size, void* d_ws, size_t ws_size,
                              hipStream_t stream) {
  const float* x    = (const float*)d_in[0];
  const float* A    = (const float*)d_in[1];
  const float* AT   = (const float*)d_in[2];
  const float* Wq   = (const float*)d_in[3];
  const float* bq   = (const float*)d_in[4];
  const float* Wk   = (const float*)d_in[5];
  const float* bk   = (const float*)d_in[6];
  const float* Wks  = (const float*)d_in[7];
  const float* bks  = (const float*)d_in[8];
  const float* Wv   = (const float*)d_in[9];
  const float* bv   = (const float*)d_in[10];
  const float* Wvs  = (const float*)d_in[11];
  const float* bvs  = (const float*)d_in[12];
  const float* Wdi  = (const float*)d_in[13];
  const float* Wdo  = (const float*)d_in[14];
  const float* Wf1  = (const float*)d_in[15];
  const float* bf1  = (const float*)d_in[16];
  const float* Wf2  = (const float*)d_in[17];
  const float* bf2  = (const float*)d_in[18];
  const float* g_ln = (const float*)d_in[19];
  const float* b_ln = (const float*)d_in[20];
  float* out = (float*)d_out;

  float* ws = (float*)d_ws;
  // layout (float units):
  // proj(bf16, 19,968,000 elems) : [0, 9,984,000)
  // bias(fp32)                   : [9,984,000, 10,406,500)
  // val (fp32)                   : [10,406,500, 14,400,100)
  // xb  (bf16, 3,993,600 elems)  : [14,400,100, 16,396,900)
  // Wcat(bf16, 20,480 elems)     : [16,396,900, 16,407,140)
  // bcat(fp32, 320)              : [16,407,140, 16,407,460)
  ushort* proj = (ushort*)ws;
  float*  bias = ws + 9984000;
  float*  val  = ws + 10406500;
  ushort* xb   = (ushort*)(ws + 14400100);
  ushort* Wcat = (ushort*)(ws + 16396900);
  float*  bcat = ws + 16407140;

  cvt_kernel<<<1950, 256, 0, stream>>>(x, xb, 499200);
  wpack_kernel<<<1, 256, 0, stream>>>(Wq, bq, Wk, bk, Wks, bks,
                                      Wv, bv, Wvs, bvs, Wcat, bcat);
  bias_kernel<<<(KH*NN2 + 255)/256, 256, 0, stream>>>(Wdi, Wdo, A, AT, bias);
  proj_kernel<<<975, 256, 0, stream>>>(xb, Wcat, bcat, proj);
  attn_kernel<<<dim3(BT, KH), 256, 0, stream>>>(proj, bias, val);
  ffn_kernel<<<15600, 256, 0, stream>>>(val, x, Wf1, bf1, Wf2, bf2,
                                        g_ln, b_ln, out);
}

// Round 3
// 314.301 us; speedup vs baseline: 4.3949x; 1.6489x over previous
//
#include <hip/hip_runtime.h>
#include <math.h>

#define NN 325
#define FD 64
#define KH 4
#define DH 16
#define BT 192
#define NN2 (NN*NN)
#define PST (NN*DH)     // 5200 elems per (proj,head,bt) slice
#define SSTR 340        // S row stride (dwords); P row = same bytes as bf16 (680)
#define VSTR 360        // vT row stride (bf16)
#define HSTR 72         // ffn LDS transpose stride (bf16)

typedef __attribute__((ext_vector_type(8))) short short8;
typedef __attribute__((ext_vector_type(4))) float f32x4;

union U8 { uint4 u; short8 s; };
__device__ inline short8 lds8(const ushort* p){ U8 t; t.u = *(const uint4*)p; return t.s; }
__device__ inline float b2f(ushort v){ return __uint_as_float(((unsigned)v) << 16); }
__device__ inline ushort f2b(float f){
  unsigned u = __float_as_uint(f);
  u += 0x7fff + ((u >> 16) & 1);
  return (ushort)(u >> 16);
}

// ---------------- x -> bf16 ----------------
__global__ __launch_bounds__(256) void cvt_kernel(const float* __restrict__ x,
                                                  ushort* __restrict__ xb, int n8){
  int i = blockIdx.x * 256 + threadIdx.x;
  if (i >= n8) return;
  const float4* xp = (const float4*)x + (size_t)i * 2;
  float4 v0 = xp[0], v1 = xp[1];
  uint4 u;
  u.x = f2b(v0.x) | ((unsigned)f2b(v0.y) << 16);
  u.y = f2b(v0.z) | ((unsigned)f2b(v0.w) << 16);
  u.z = f2b(v1.x) | ((unsigned)f2b(v1.y) << 16);
  u.w = f2b(v1.z) | ((unsigned)f2b(v1.w) << 16);
  ((uint4*)xb)[i] = u;
}

// ---------------- pack W's -> Wcat bf16 [448][64] ----------------
// rows 0..319: Wq,Wk,Wks,Wv,Wvs ; 320..383: Wf1 ; 384..447: Wf2
__global__ __launch_bounds__(256) void wpack_kernel(
    const float* __restrict__ Wq,  const float* __restrict__ bq,
    const float* __restrict__ Wk,  const float* __restrict__ bk,
    const float* __restrict__ Wks, const float* __restrict__ bks,
    const float* __restrict__ Wv,  const float* __restrict__ bv,
    const float* __restrict__ Wvs, const float* __restrict__ bvs,
    const float* __restrict__ Wf1, const float* __restrict__ Wf2,
    ushort* __restrict__ Wcat, float* __restrict__ bcat){
  const float* Ws[7] = {Wq, Wk, Wks, Wv, Wvs, Wf1, Wf2};
  const float* bs[5] = {bq, bk, bks, bv, bvs};
  for (int f = threadIdx.x; f < 448; f += 256){
    int p = f >> 6, fl = f & 63;
    const float* wr = Ws[p] + fl * 64;
    unsigned* dst = (unsigned*)Wcat + f * 32;
    #pragma unroll
    for (int c = 0; c < 32; ++c)
      dst[c] = f2b(wr[2*c]) | ((unsigned)f2b(wr[2*c+1]) << 16);
    if (f < 320) bcat[f] = bs[p][fl];
  }
}

// ---------------- bias: [4][N][N] ----------------
__global__ __launch_bounds__(256) void bias_kernel(
    const float* __restrict__ Wdi, const float* __restrict__ Wdo,
    const float* __restrict__ A,   const float* __restrict__ AT,
    float* __restrict__ bias){
  int idx = blockIdx.x * 256 + threadIdx.x;
  if (idx >= KH * NN2) return;
  int h = idx / NN2, r = idx - h * NN2;
  float s = 0.f;
  if (h < 2){
    #pragma unroll
    for (int k = 0; k < 3; ++k) s += Wdi[(h*3 + k)*NN2 + r] * A[k*NN2 + r];
  } else {
    int h2 = h - 2;
    #pragma unroll
    for (int k = 0; k < 3; ++k) s += Wdo[(h2*3 + k)*NN2 + r] * AT[k*NN2 + r];
  }
  bias[idx] = s;
}

// ---------------- projections via MFMA: proj bf16 [p][h][bt][n][d] ----------------
__global__ __launch_bounds__(256) void proj_kernel(
    const ushort* __restrict__ xb, const ushort* __restrict__ Wcat,
    const float* __restrict__ bcat, ushort* __restrict__ proj){
  int tid = threadIdx.x, lane = tid & 63, wid = tid >> 6;
  int r0 = blockIdx.x * 64 + wid * 16;
  int m = lane & 15, kc = lane >> 4;     // A row, k-chunk
  short8 a0 = lds8(xb + ((size_t)(r0 + m) * 64 + kc * 8));
  short8 a1 = lds8(xb + ((size_t)(r0 + m) * 64 + kc * 8 + 32));
  int btA[4], nA[4];
  #pragma unroll
  for (int rg = 0; rg < 4; ++rg){
    int gr = r0 + kc * 4 + rg;           // C row = (lane>>4)*4 + rg
    btA[rg] = gr / NN; nA[rg] = gr - btA[rg] * NN;
  }
  for (int ct = 0; ct < 20; ++ct){
    short8 b0 = lds8(Wcat + ((size_t)(ct*16 + m) * 64 + kc * 8));
    short8 b1 = lds8(Wcat + ((size_t)(ct*16 + m) * 64 + kc * 8 + 32));
    float bv = bcat[ct*16 + m];
    f32x4 acc = {bv, bv, bv, bv};
    acc = __builtin_amdgcn_mfma_f32_16x16x32_bf16(a0, b0, acc, 0, 0, 0);
    acc = __builtin_amdgcn_mfma_f32_16x16x32_bf16(a1, b1, acc, 0, 0, 0);
    #pragma unroll
    for (int rg = 0; rg < 4; ++rg){
      size_t addr = ((size_t)ct * BT + btA[rg]) * PST + nA[rg] * 16 + m;
      proj[addr] = f2b(acc[rg]);
    }
  }
}

// ---------------- attention via MFMA ----------------
// grid (192, 4) = (bt, h); 256 threads = 4 waves = 2 wave-pairs, 2 Q-tiles in flight.
__global__ __launch_bounds__(256) void attn_kernel(
    const ushort* __restrict__ proj, const float* __restrict__ bias,
    ushort* __restrict__ val){
  __shared__ float  S[2][16 * SSTR];   // fp32 scores; reused in-place as bf16 P
  __shared__ ushort vT[16 * VSTR];     // transposed V
  __shared__ float  es[336];
  __shared__ float  rstat[2][16][2];   // {inv, 1-asum}
  int h = blockIdx.y, bt = blockIdx.x;
  int tid = threadIdx.x, lane = tid & 63, wid = tid >> 6;
  int slot = wid >> 1, half = wid & 1;
  const ushort* qb  = proj + (size_t)((0*4 + h)*BT + bt) * PST;
  const ushort* kb  = proj + (size_t)((1*4 + h)*BT + bt) * PST;
  const ushort* ksb = proj + (size_t)((2*4 + h)*BT + bt) * PST;
  const ushort* vb  = proj + (size_t)((3*4 + h)*BT + bt) * PST;
  const ushort* vsb = proj + (size_t)((4*4 + h)*BT + bt) * PST;

  // stage vT (transpose V), zero padding cols
  for (int i = tid; i < 2600; i += 256){
    unsigned u = ((const unsigned*)vb)[i];
    int n = (2*i) >> 4, d = (2*i) & 15;
    vT[d*VSTR + n]       = (ushort)(u & 0xffff);
    vT[(d+1)*VSTR + n]   = (ushort)(u >> 16);
  }
  for (int i = tid; i < 16*35; i += 256){
    int d = i / 35, mm = 325 + i % 35;
    vT[d*VSTR + mm] = 0;
  }
  // es = sigmoid(q . ks / 4)
  for (int n = tid; n < 336; n += 256){
    float s = 1.0f;
    if (n < 325){
      const unsigned* qp = (const unsigned*)(qb + (size_t)n * 16);
      const unsigned* kp = (const unsigned*)(ksb + (size_t)n * 16);
      float dot = 0.f;
      #pragma unroll
      for (int c = 0; c < 8; ++c){
        unsigned qv = qp[c], kv = kp[c];
        dot += b2f((ushort)(qv & 0xffff)) * b2f((ushort)(kv & 0xffff))
             + b2f((ushort)(qv >> 16))    * b2f((ushort)(kv >> 16));
      }
      s = 1.f / (1.f + expf(-dot * 0.25f));
    }
    es[n] = s;
  }
  __syncthreads();

  const float NEG = -1e30f;
  for (int t = 0; t < 11; ++t){
    int qt = t * 2 + slot;
    bool act = (qt < 21);
    // ---- S phase: S = Q K^T (raw dot), halves split col-tiles ----
    if (act){
      int m = lane & 15, kc = lane >> 4;
      short8 aq = {0,0,0,0,0,0,0,0};
      if (kc < 2)
        aq = lds8(qb + ((size_t)(qt*16 + m) * 16 + kc * 8));
      int c0 = half ? 11 : 0, c1 = half ? 21 : 11;
      for (int ct = c0; ct < c1; ++ct){
        short8 bk = {0,0,0,0,0,0,0,0};
        if (kc < 2)
          bk = lds8(kb + ((size_t)(ct*16 + m) * 16 + kc * 8));
        f32x4 acc = {0.f, 0.f, 0.f, 0.f};
        acc = __builtin_amdgcn_mfma_f32_16x16x32_bf16(aq, bk, acc, 0, 0, 0);
        float* sp = &S[slot][0];
        int col = ct*16 + m, rb = kc * 4;
        #pragma unroll
        for (int rg = 0; rg < 4; ++rg) sp[(rb + rg)*SSTR + col] = acc[rg];
      }
    }
    __syncthreads();
    // ---- softmax (rows split across halves) ----
    if (act){
      int r = half * 8 + (lane >> 3), c = lane & 7;
      int n = qt * 16 + r;
      int nb = min(n, NN - 1);
      const float* bp = bias + (size_t)h * NN2 + (size_t)nb * NN;
      float* sr = &S[slot][r * SSTR];
      float mx = NEG;
      #pragma unroll
      for (int j = 0; j < 11; ++j){
        int m0 = c * 4 + 32 * j;
        if (m0 < 336){
          float4 e4 = *(float4*)(sr + m0);
          float e0 = (m0+0 < NN) ? e4.x * 0.25f + bp[m0+0] : NEG;
          float e1 = (m0+1 < NN) ? e4.y * 0.25f + bp[m0+1] : NEG;
          float e2 = (m0+2 < NN) ? e4.z * 0.25f + bp[m0+2] : NEG;
          float e3 = (m0+3 < NN) ? e4.w * 0.25f + bp[m0+3] : NEG;
          *(float4*)(sr + m0) = make_float4(e0, e1, e2, e3);
          mx = fmaxf(mx, fmaxf(fmaxf(e0, e1), fmaxf(e2, e3)));
        }
      }
      mx = fmaxf(mx, __shfl_xor(mx, 1, 64));
      mx = fmaxf(mx, __shfl_xor(mx, 2, 64));
      mx = fmaxf(mx, __shfl_xor(mx, 4, 64));
      float sum = 0.f;
      ushort* pr = (ushort*)sr;          // P row (bf16), capacity 680
      #pragma unroll
      for (int j = 0; j < 11; ++j){
        int m0 = c * 4 + 32 * j;
        if (m0 < 336){
          float4 e4 = *(float4*)(sr + m0);
          float x0 = expf(e4.x - mx), x1 = expf(e4.y - mx);
          float x2 = expf(e4.z - mx), x3 = expf(e4.w - mx);
          ushort p0 = f2b(x0), p1 = f2b(x1), p2 = f2b(x2), p3 = f2b(x3);
          sum += b2f(p0) + b2f(p1) + b2f(p2) + b2f(p3);
          uint2 w;
          w.x = p0 | ((unsigned)p1 << 16);
          w.y = p2 | ((unsigned)p3 << 16);
          *(uint2*)(pr + m0) = w;
        } else {                          // m0 in [336,352): zero P tail
          *(uint2*)(pr + m0) = make_uint2(0u, 0u);
        }
      }
      sum += __shfl_xor(sum, 1, 64);
      sum += __shfl_xor(sum, 2, 64);
      sum += __shfl_xor(sum, 4, 64);
      float iv = 1.f / (es[n] + sum);
      if (c == 0){ rstat[slot][r][0] = iv; rstat[slot][r][1] = 1.f - sum * iv; }
    }
    __syncthreads();
    // ---- PV + epilogue (half 0 only) ----
    if (act && half == 0){
      int d = lane & 15, kc = lane >> 4;
      const ushort* prow = (const ushort*)&S[slot][0] + (size_t)d * (SSTR * 2);
      const ushort* vrow = &vT[d * VSTR];
      f32x4 acc = {0.f, 0.f, 0.f, 0.f};
      #pragma unroll
      for (int tt = 0; tt < 11; ++tt){
        short8 ap = lds8(prow + kc * 8 + 32 * tt);
        short8 bv = lds8(vrow + kc * 8 + 32 * tt);
        acc = __builtin_amdgcn_mfma_f32_16x16x32_bf16(ap, bv, acc, 0, 0, 0);
      }
      #pragma unroll
      for (int rg = 0; rg < 4; ++rg){
        int r = kc * 4 + rg, n = qt * 16 + r;
        if (n < NN){
          float iv = rstat[slot][r][0], om = rstat[slot][r][1];
          float vs = b2f(vsb[(size_t)n * 16 + d]);
          val[((size_t)bt * NN + n) * FD + h * 16 + d] =
              f2b(acc[rg] * iv + om * vs);
        }
      }
    }
    __syncthreads();
  }
}

// ---------------- FFN + residual + LayerNorm via MFMA ----------------
// block 256 = 4 waves, wave = 16 rows; grid 975
__global__ __launch_bounds__(256) void ffn_kernel(
    const ushort* __restrict__ val, const float* __restrict__ x,
    const ushort* __restrict__ Wf1b, const float* __restrict__ bf1,
    const ushort* __restrict__ Wf2b, const float* __restrict__ bf2,
    const float* __restrict__ g_ln, const float* __restrict__ b_ln,
    float* __restrict__ out){
  __shared__ ushort hs[4][16 * HSTR];
  int tid = threadIdx.x, lane = tid & 63, wid = tid >> 6;
  int m = lane & 15, kc = lane >> 4;
  int r0 = blockIdx.x * 64 + wid * 16;

  // GEMM1: h1 = gelu(val @ Wf1^T + bf1)
  short8 a0 = lds8(val + ((size_t)(r0 + m) * 64 + kc * 8));
  short8 a1 = lds8(val + ((size_t)(r0 + m) * 64 + kc * 8 + 32));
  f32x4 acc1[4];
  #pragma unroll
  for (int ct = 0; ct < 4; ++ct){
    short8 b0 = lds8(Wf1b + ((size_t)(ct*16 + m) * 64 + kc * 8));
    short8 b1 = lds8(Wf1b + ((size_t)(ct*16 + m) * 64 + kc * 8 + 32));
    float bv = bf1[ct*16 + m];
    f32x4 acc = {bv, bv, bv, bv};
    acc = __builtin_amdgcn_mfma_f32_16x16x32_bf16(a0, b0, acc, 0, 0, 0);
    acc1[ct] = __builtin_amdgcn_mfma_f32_16x16x32_bf16(a1, b1, acc, 0, 0, 0);
  }
  // GELU (exact) -> bf16 -> LDS transpose (C-layout -> A-layout)
  #pragma unroll
  for (int ct = 0; ct < 4; ++ct){
    #pragma unroll
    for (int rg = 0; rg < 4; ++rg){
      float t = acc1[ct][rg];
      float g = 0.5f * t * (1.f + erff(t * 0.70710678118654752f));
      hs[wid][(kc*4 + rg) * HSTR + ct*16 + m] = f2b(g);
    }
  }
  __syncthreads();
  short8 h0 = lds8(&hs[wid][m * HSTR + kc * 8]);
  short8 h1 = lds8(&hs[wid][m * HSTR + kc * 8 + 32]);

  // GEMM2: t = h1 @ Wf2^T + bf2 + x
  f32x4 acc2[4];
  #pragma unroll
  for (int ct = 0; ct < 4; ++ct){
    short8 b0 = lds8(Wf2b + ((size_t)(ct*16 + m) * 64 + kc * 8));
    short8 b1 = lds8(Wf2b + ((size_t)(ct*16 + m) * 64 + kc * 8 + 32));
    float bv = bf2[ct*16 + m];
    f32x4 acc = {bv, bv, bv, bv};
    acc = __builtin_amdgcn_mfma_f32_16x16x32_bf16(h0, b0, acc, 0, 0, 0);
    acc2[ct] = __builtin_amdgcn_mfma_f32_16x16x32_bf16(h1, b1, acc, 0, 0, 0);
  }
  // residual + LayerNorm (rows kc*4+rg live in this 16-lane group)
  float t[4][4];
  #pragma unroll
  for (int ct = 0; ct < 4; ++ct){
    #pragma unroll
    for (int rg = 0; rg < 4; ++rg)
      t[ct][rg] = acc2[ct][rg] + x[(size_t)(r0 + kc*4 + rg) * 64 + ct*16 + m];
  }
  float mu[4], rs[4];
  #pragma unroll
  for (int rg = 0; rg < 4; ++rg){
    float s = t[0][rg] + t[1][rg] + t[2][rg] + t[3][rg];
    s += __shfl_xor(s, 1, 64); s += __shfl_xor(s, 2, 64);
    s += __shfl_xor(s, 4, 64); s += __shfl_xor(s, 8, 64);
    mu[rg] = s * (1.f/64.f);
  }
  #pragma unroll
  for (int rg = 0; rg < 4; ++rg){
    float d0 = t[0][rg]-mu[rg], d1 = t[1][rg]-mu[rg];
    float d2 = t[2][rg]-mu[rg], d3 = t[3][rg]-mu[rg];
    float s = d0*d0 + d1*d1 + d2*d2 + d3*d3;
    s += __shfl_xor(s, 1, 64); s += __shfl_xor(s, 2, 64);
    s += __shfl_xor(s, 4, 64); s += __shfl_xor(s, 8, 64);
    rs[rg] = rsqrtf(s * (1.f/64.f) + 1e-5f);
  }
  #pragma unroll
  for (int ct = 0; ct < 4; ++ct){
    float g = g_ln[ct*16 + m], b = b_ln[ct*16 + m];
    #pragma unroll
    for (int rg = 0; rg < 4; ++rg)
      out[(size_t)(r0 + kc*4 + rg) * 64 + ct*16 + m] =
          g * (t[ct][rg] - mu[rg]) * rs[rg] + b;
  }
}

extern "C" void kernel_launch(void* const* d_in, const int* in_sizes, int n_in,
                              void* d_out, int out_size, void* d_ws, size_t ws_size,
                              hipStream_t stream) {
  const float* x    = (const float*)d_in[0];
  const float* A    = (const float*)d_in[1];
  const float* AT   = (const float*)d_in[2];
  const float* Wq   = (const float*)d_in[3];
  const float* bq   = (const float*)d_in[4];
  const float* Wk   = (const float*)d_in[5];
  const float* bk   = (const float*)d_in[6];
  const float* Wks  = (const float*)d_in[7];
  const float* bks  = (const float*)d_in[8];
  const float* Wv   = (const float*)d_in[9];
  const float* bv   = (const float*)d_in[10];
  const float* Wvs  = (const float*)d_in[11];
  const float* bvs  = (const float*)d_in[12];
  const float* Wdi  = (const float*)d_in[13];
  const float* Wdo  = (const float*)d_in[14];
  const float* Wf1  = (const float*)d_in[15];
  const float* bf1  = (const float*)d_in[16];
  const float* Wf2  = (const float*)d_in[17];
  const float* bf2  = (const float*)d_in[18];
  const float* g_ln = (const float*)d_in[19];
  const float* b_ln = (const float*)d_in[20];
  float* out = (float*)d_out;

  float* ws = (float*)d_ws;
  // layout (float units):
  // proj(bf16, 19,968,000 elems) : [0, 9,984,000)
  // bias(fp32)                   : [9,984,000, 10,406,500)
  // val (bf16, 3,993,600 elems)  : [10,406,500, 12,403,300)
  // xb  (bf16, 3,993,600 elems)  : [14,400,100, 16,396,900)
  // Wcat(bf16, 28,672 elems)     : [16,396,900, 16,411,236)
  // bcat(fp32, 320)              : [16,411,236, 16,411,556)
  ushort* proj = (ushort*)ws;
  float*  bias = ws + 9984000;
  ushort* val  = (ushort*)(ws + 10406500);
  ushort* xb   = (ushort*)(ws + 14400100);
  ushort* Wcat = (ushort*)(ws + 16396900);
  float*  bcat = ws + 16411236;
  ushort* Wf1b = Wcat + 320*64;
  ushort* Wf2b = Wcat + 384*64;

  cvt_kernel<<<1950, 256, 0, stream>>>(x, xb, 499200);
  wpack_kernel<<<1, 256, 0, stream>>>(Wq, bq, Wk, bk, Wks, bks,
                                      Wv, bv, Wvs, bvs, Wf1, Wf2, Wcat, bcat);
  bias_kernel<<<(KH*NN2 + 255)/256, 256, 0, stream>>>(Wdi, Wdo, A, AT, bias);
  proj_kernel<<<975, 256, 0, stream>>>(xb, Wcat, bcat, proj);
  attn_kernel<<<dim3(BT, KH), 256, 0, stream>>>(proj, bias, val);
  ffn_kernel<<<975, 256, 0, stream>>>(val, x, Wf1b, bf1, Wf2b, bf2,
                                      g_ln, b_ln, out);
}

// Round 4
// 234.911 us; speedup vs baseline: 5.8802x; 1.3380x over previous
//
#include <hip/hip_runtime.h>
#include <math.h>

#define NN 325
#define FD 64
#define KH 4
#define DH 16
#define BT 192
#define NN2 (NN*NN)
#define PST (NN*DH)     // 5200 elems per (proj,head,bt) slice
#define SSTR 340        // attn S row stride (dwords); P row in-place bf16
#define BSTR 352        // padded bias row stride (floats)
#define VTS  352        // vT row stride (bf16)
#define VSLICE (16*VTS) // vT per-(h,bt) slice
#define HSTR 72         // ffn LDS transpose stride (bf16)

typedef __attribute__((ext_vector_type(8))) short short8;
typedef __attribute__((ext_vector_type(4))) float f32x4;

union U8 { uint4 u; short8 s; };
__device__ inline short8 lds8(const ushort* p){ U8 t; t.u = *(const uint4*)p; return t.s; }
__device__ inline float b2f(ushort v){ return __uint_as_float(((unsigned)v) << 16); }
__device__ inline ushort f2b(float f){
  unsigned u = __float_as_uint(f);
  u += 0x7fff + ((u >> 16) & 1);
  return (ushort)(u >> 16);
}
__device__ inline short8 cvt8(const float* p){
  float4 u = ((const float4*)p)[0], v = ((const float4*)p)[1];
  union { ushort us[8]; short8 s; } t;
  t.us[0]=f2b(u.x); t.us[1]=f2b(u.y); t.us[2]=f2b(u.z); t.us[3]=f2b(u.w);
  t.us[4]=f2b(v.x); t.us[5]=f2b(v.y); t.us[6]=f2b(v.z); t.us[7]=f2b(v.w);
  return t.s;
}

// ---------------- pack W's -> Wcat bf16 [448][64] ----------------
__global__ __launch_bounds__(256) void wpack_kernel(
    const float* __restrict__ Wq,  const float* __restrict__ bq,
    const float* __restrict__ Wk,  const float* __restrict__ bk,
    const float* __restrict__ Wks, const float* __restrict__ bks,
    const float* __restrict__ Wv,  const float* __restrict__ bv,
    const float* __restrict__ Wvs, const float* __restrict__ bvs,
    const float* __restrict__ Wf1, const float* __restrict__ Wf2,
    ushort* __restrict__ Wcat, float* __restrict__ bcat){
  const float* Ws[7] = {Wq, Wk, Wks, Wv, Wvs, Wf1, Wf2};
  const float* bs[5] = {bq, bk, bks, bv, bvs};
  for (int f = threadIdx.x; f < 448; f += 256){
    int p = f >> 6, fl = f & 63;
    const float* wr = Ws[p] + fl * 64;
    unsigned* dst = (unsigned*)Wcat + f * 32;
    #pragma unroll
    for (int c = 0; c < 32; ++c)
      dst[c] = f2b(wr[2*c]) | ((unsigned)f2b(wr[2*c+1]) << 16);
    if (f < 320) bcat[f] = bs[p][fl];
  }
}

// ---------------- bias padded: [4][325][352], pad cols = -1e30 ----------------
__global__ __launch_bounds__(256) void bias_kernel(
    const float* __restrict__ Wdi, const float* __restrict__ Wdo,
    const float* __restrict__ A,   const float* __restrict__ AT,
    float* __restrict__ biasP){
  int idx = blockIdx.x * 256 + threadIdx.x;
  if (idx >= KH * NN * BSTR) return;
  int h = idx / (NN * BSTR), rem = idx - h * (NN * BSTR);
  int n = rem / BSTR, m = rem - n * BSTR;
  float s = -1e30f;
  if (m < NN){
    int r = n * NN + m;
    s = 0.f;
    if (h < 2){
      #pragma unroll
      for (int k = 0; k < 3; ++k) s += Wdi[(h*3 + k)*NN2 + r] * A[k*NN2 + r];
    } else {
      int h2 = h - 2;
      #pragma unroll
      for (int k = 0; k < 3; ++k) s += Wdo[(h2*3 + k)*NN2 + r] * AT[k*NN2 + r];
    }
  }
  biasP[idx] = s;
}

// ---------------- projections via MFMA (x fp32 -> bf16 in-reg) ----------------
__global__ __launch_bounds__(256) void proj_kernel(
    const float* __restrict__ x, const ushort* __restrict__ Wcat,
    const float* __restrict__ bcat, ushort* __restrict__ proj){
  int tid = threadIdx.x, lane = tid & 63, wid = tid >> 6;
  int r0 = blockIdx.x * 64 + wid * 16;
  int m = lane & 15, kc = lane >> 4;
  const float* xr = x + (size_t)(r0 + m) * 64 + kc * 8;
  short8 a0 = cvt8(xr);
  short8 a1 = cvt8(xr + 32);
  int btA[4], nA[4];
  #pragma unroll
  for (int rg = 0; rg < 4; ++rg){
    int gr = r0 + kc * 4 + rg;
    btA[rg] = gr / NN; nA[rg] = gr - btA[rg] * NN;
  }
  for (int ct = 0; ct < 20; ++ct){
    short8 b0 = lds8(Wcat + ((size_t)(ct*16 + m) * 64 + kc * 8));
    short8 b1 = lds8(Wcat + ((size_t)(ct*16 + m) * 64 + kc * 8 + 32));
    float bv = bcat[ct*16 + m];
    f32x4 acc = {bv, bv, bv, bv};
    acc = __builtin_amdgcn_mfma_f32_16x16x32_bf16(a0, b0, acc, 0, 0, 0);
    acc = __builtin_amdgcn_mfma_f32_16x16x32_bf16(a1, b1, acc, 0, 0, 0);
    #pragma unroll
    for (int rg = 0; rg < 4; ++rg){
      size_t addr = ((size_t)ct * BT + btA[rg]) * PST + nA[rg] * 16 + m;
      proj[addr] = f2b(acc[rg]);
    }
  }
}

// ---------------- V transpose: [n][d] -> vT[h][bt][d][352], pad zeroed ----------------
__global__ __launch_bounds__(256) void vtrans_kernel(
    const ushort* __restrict__ proj, ushort* __restrict__ vt){
  int bt = blockIdx.x, h = blockIdx.y, tid = threadIdx.x;
  const unsigned* vb = (const unsigned*)(proj + (size_t)((3*KH + h)*BT + bt) * PST);
  ushort* vs = vt + (size_t)(h*BT + bt) * VSLICE;
  for (int i = tid; i < 2600; i += 256){
    unsigned u = vb[i];
    int n = i >> 3, d = 2 * (i & 7);
    vs[d*VTS + n]     = (ushort)(u & 0xffff);
    vs[(d+1)*VTS + n] = (ushort)(u >> 16);
  }
  for (int i = tid; i < 16*27; i += 256){
    int d = i / 27, n = NN + i % 27;
    vs[d*VTS + n] = 0;
  }
}

// ---------------- attention: one block per (qt, bt, h) ----------------
__global__ __launch_bounds__(256, 4) void attn_kernel(
    const ushort* __restrict__ proj, const float* __restrict__ biasP,
    const ushort* __restrict__ vt, ushort* __restrict__ val){
  __shared__ float S[16 * SSTR];       // fp32 scores; P in-place bf16
  __shared__ float part[4][16][16];    // PV partials per wave
  __shared__ float rstat[16][2];       // {inv, 1-asum}
  int qt = blockIdx.x, bt = blockIdx.y, h = blockIdx.z;
  int tid = threadIdx.x, lane = tid & 63, wid = tid >> 6;
  const ushort* qb  = proj + (size_t)((0*KH + h)*BT + bt) * PST;
  const ushort* kb  = proj + (size_t)((1*KH + h)*BT + bt) * PST;
  const ushort* ksb = proj + (size_t)((2*KH + h)*BT + bt) * PST;
  const ushort* vsb = proj + (size_t)((4*KH + h)*BT + bt) * PST;
  const ushort* vtg = vt + (size_t)(h*BT + bt) * VSLICE;

  // ---- S = Q K^T: 21 col-tiles split across 4 waves ----
  {
    int m = lane & 15, kc = lane >> 4;
    short8 zero = {0,0,0,0,0,0,0,0};
    short8 aq = (kc < 2) ? lds8(qb + ((size_t)(qt*16 + m) * 16 + kc * 8)) : zero;
    for (int ct = wid; ct < 21; ct += 4){
      short8 bk = (kc < 2) ? lds8(kb + ((size_t)(ct*16 + m) * 16 + kc * 8)) : zero;
      f32x4 acc = {0.f, 0.f, 0.f, 0.f};
      acc = __builtin_amdgcn_mfma_f32_16x16x32_bf16(aq, bk, acc, 0, 0, 0);
      #pragma unroll
      for (int rg = 0; rg < 4; ++rg)
        S[(kc*4 + rg)*SSTR + ct*16 + m] = acc[rg];
    }
  }
  __syncthreads();

  // ---- softmax: 16 lanes per row ----
  {
    int r = tid >> 4, c = tid & 15;
    int n = qt * 16 + r;
    int nb = min(n, NN - 1);
    // es = sigmoid(q . ks / 4): lane c handles d=c
    float dp = b2f(qb[(size_t)nb * 16 + c]) * b2f(ksb[(size_t)nb * 16 + c]);
    dp += __shfl_xor(dp, 1, 64); dp += __shfl_xor(dp, 2, 64);
    dp += __shfl_xor(dp, 4, 64); dp += __shfl_xor(dp, 8, 64);
    float esv = 1.f / (1.f + __expf(-dp * 0.25f));

    const float* bp = biasP + (size_t)(h*NN + nb) * BSTR;
    float* sr = S + r * SSTR;
    float4 ev[6];
    float mx = -3.0e38f;
    #pragma unroll
    for (int j = 0; j < 6; ++j){
      int m0 = c * 4 + 64 * j;
      if (m0 < 336){
        float4 sv = *(const float4*)(sr + m0);
        float4 bb = *(const float4*)(bp + m0);
        float4 e;
        e.x = fmaf(sv.x, 0.25f, bb.x);
        e.y = fmaf(sv.y, 0.25f, bb.y);
        e.z = fmaf(sv.z, 0.25f, bb.z);
        e.w = fmaf(sv.w, 0.25f, bb.w);
        ev[j] = e;
        mx = fmaxf(mx, fmaxf(fmaxf(e.x, e.y), fmaxf(e.z, e.w)));
      } else {
        ev[j] = make_float4(-1e30f, -1e30f, -1e30f, -1e30f);
      }
    }
    mx = fmaxf(mx, __shfl_xor(mx, 1, 64));
    mx = fmaxf(mx, __shfl_xor(mx, 2, 64));
    mx = fmaxf(mx, __shfl_xor(mx, 4, 64));
    mx = fmaxf(mx, __shfl_xor(mx, 8, 64));
    float sum = 0.f;
    ushort* pr = (ushort*)sr;
    #pragma unroll
    for (int j = 0; j < 6; ++j){
      int m0 = c * 4 + 64 * j;
      if (m0 < 352){
        float4 e = ev[j];
        ushort p0 = f2b(__expf(e.x - mx)), p1 = f2b(__expf(e.y - mx));
        ushort p2 = f2b(__expf(e.z - mx)), p3 = f2b(__expf(e.w - mx));
        sum += b2f(p0) + b2f(p1) + b2f(p2) + b2f(p3);
        uint2 w;
        w.x = p0 | ((unsigned)p1 << 16);
        w.y = p2 | ((unsigned)p3 << 16);
        *(uint2*)(pr + m0) = w;
      }
    }
    sum += __shfl_xor(sum, 1, 64); sum += __shfl_xor(sum, 2, 64);
    sum += __shfl_xor(sum, 4, 64); sum += __shfl_xor(sum, 8, 64);
    float iv = 1.f / (esv + sum);
    if (c == 0){ rstat[r][0] = iv; rstat[r][1] = 1.f - sum * iv; }
  }
  __syncthreads();

  // ---- PV: 11 K-steps split across 4 waves ----
  {
    int d = lane & 15, kc = lane >> 4;
    const ushort* prow = (const ushort*)S + (size_t)(lane & 15) * (SSTR * 2);
    f32x4 acc = {0.f, 0.f, 0.f, 0.f};
    for (int tt = wid; tt < 11; tt += 4){
      short8 ap = lds8(prow + tt*32 + kc*8);
      short8 bv = lds8(vtg + (size_t)d * VTS + tt*32 + kc*8);
      acc = __builtin_amdgcn_mfma_f32_16x16x32_bf16(ap, bv, acc, 0, 0, 0);
    }
    #pragma unroll
    for (int rg = 0; rg < 4; ++rg)
      part[wid][kc*4 + rg][d] = acc[rg];
  }
  __syncthreads();

  // ---- epilogue: 256 threads, one (row, d) each ----
  {
    int r = tid >> 4, d = tid & 15;
    int n = qt * 16 + r;
    if (n < NN){
      float s = part[0][r][d] + part[1][r][d] + part[2][r][d] + part[3][r][d];
      float res = s * rstat[r][0] + rstat[r][1] * b2f(vsb[(size_t)n * 16 + d]);
      val[((size_t)bt * NN + n) * FD + h * 16 + d] = f2b(res);
    }
  }
}

// ---------------- FFN + residual + LayerNorm via MFMA ----------------
__global__ __launch_bounds__(256) void ffn_kernel(
    const ushort* __restrict__ val, const float* __restrict__ x,
    const ushort* __restrict__ Wf1b, const float* __restrict__ bf1,
    const ushort* __restrict__ Wf2b, const float* __restrict__ bf2,
    const float* __restrict__ g_ln, const float* __restrict__ b_ln,
    float* __restrict__ out){
  __shared__ ushort hs[4][16 * HSTR];
  int tid = threadIdx.x, lane = tid & 63, wid = tid >> 6;
  int m = lane & 15, kc = lane >> 4;
  int r0 = blockIdx.x * 64 + wid * 16;

  short8 a0 = lds8(val + ((size_t)(r0 + m) * 64 + kc * 8));
  short8 a1 = lds8(val + ((size_t)(r0 + m) * 64 + kc * 8 + 32));
  f32x4 acc1[4];
  #pragma unroll
  for (int ct = 0; ct < 4; ++ct){
    short8 b0 = lds8(Wf1b + ((size_t)(ct*16 + m) * 64 + kc * 8));
    short8 b1 = lds8(Wf1b + ((size_t)(ct*16 + m) * 64 + kc * 8 + 32));
    float bv = bf1[ct*16 + m];
    f32x4 acc = {bv, bv, bv, bv};
    acc = __builtin_amdgcn_mfma_f32_16x16x32_bf16(a0, b0, acc, 0, 0, 0);
    acc1[ct] = __builtin_amdgcn_mfma_f32_16x16x32_bf16(a1, b1, acc, 0, 0, 0);
  }
  #pragma unroll
  for (int ct = 0; ct < 4; ++ct){
    #pragma unroll
    for (int rg = 0; rg < 4; ++rg){
      float t = acc1[ct][rg];
      float g = 0.5f * t * (1.f + erff(t * 0.70710678118654752f));
      hs[wid][(kc*4 + rg) * HSTR + ct*16 + m] = f2b(g);
    }
  }
  __syncthreads();
  short8 h0 = lds8(&hs[wid][m * HSTR + kc * 8]);
  short8 h1 = lds8(&hs[wid][m * HSTR + kc * 8 + 32]);

  f32x4 acc2[4];
  #pragma unroll
  for (int ct = 0; ct < 4; ++ct){
    short8 b0 = lds8(Wf2b + ((size_t)(ct*16 + m) * 64 + kc * 8));
    short8 b1 = lds8(Wf2b + ((size_t)(ct*16 + m) * 64 + kc * 8 + 32));
    float bv = bf2[ct*16 + m];
    f32x4 acc = {bv, bv, bv, bv};
    acc = __builtin_amdgcn_mfma_f32_16x16x32_bf16(h0, b0, acc, 0, 0, 0);
    acc2[ct] = __builtin_amdgcn_mfma_f32_16x16x32_bf16(h1, b1, acc, 0, 0, 0);
  }
  float t[4][4];
  #pragma unroll
  for (int ct = 0; ct < 4; ++ct){
    #pragma unroll
    for (int rg = 0; rg < 4; ++rg)
      t[ct][rg] = acc2[ct][rg] + x[(size_t)(r0 + kc*4 + rg) * 64 + ct*16 + m];
  }
  float mu[4], rs[4];
  #pragma unroll
  for (int rg = 0; rg < 4; ++rg){
    float s = t[0][rg] + t[1][rg] + t[2][rg] + t[3][rg];
    s += __shfl_xor(s, 1, 64); s += __shfl_xor(s, 2, 64);
    s += __shfl_xor(s, 4, 64); s += __shfl_xor(s, 8, 64);
    mu[rg] = s * (1.f/64.f);
  }
  #pragma unroll
  for (int rg = 0; rg < 4; ++rg){
    float d0 = t[0][rg]-mu[rg], d1 = t[1][rg]-mu[rg];
    float d2 = t[2][rg]-mu[rg], d3 = t[3][rg]-mu[rg];
    float s = d0*d0 + d1*d1 + d2*d2 + d3*d3;
    s += __shfl_xor(s, 1, 64); s += __shfl_xor(s, 2, 64);
    s += __shfl_xor(s, 4, 64); s += __shfl_xor(s, 8, 64);
    rs[rg] = rsqrtf(s * (1.f/64.f) + 1e-5f);
  }
  #pragma unroll
  for (int ct = 0; ct < 4; ++ct){
    float g = g_ln[ct*16 + m], b = b_ln[ct*16 + m];
    #pragma unroll
    for (int rg = 0; rg < 4; ++rg)
      out[(size_t)(r0 + kc*4 + rg) * 64 + ct*16 + m] =
          g * (t[ct][rg] - mu[rg]) * rs[rg] + b;
  }
}

extern "C" void kernel_launch(void* const* d_in, const int* in_sizes, int n_in,
                              void* d_out, int out_size, void* d_ws, size_t ws_size,
                              hipStream_t stream) {
  const float* x    = (const float*)d_in[0];
  const float* A    = (const float*)d_in[1];
  const float* AT   = (const float*)d_in[2];
  const float* Wq   = (const float*)d_in[3];
  const float* bq   = (const float*)d_in[4];
  const float* Wk   = (const float*)d_in[5];
  const float* bk   = (const float*)d_in[6];
  const float* Wks  = (const float*)d_in[7];
  const float* bks  = (const float*)d_in[8];
  const float* Wv   = (const float*)d_in[9];
  const float* bv   = (const float*)d_in[10];
  const float* Wvs  = (const float*)d_in[11];
  const float* bvs  = (const float*)d_in[12];
  const float* Wdi  = (const float*)d_in[13];
  const float* Wdo  = (const float*)d_in[14];
  const float* Wf1  = (const float*)d_in[15];
  const float* bf1  = (const float*)d_in[16];
  const float* Wf2  = (const float*)d_in[17];
  const float* bf2  = (const float*)d_in[18];
  const float* g_ln = (const float*)d_in[19];
  const float* b_ln = (const float*)d_in[20];
  float* out = (float*)d_out;

  float* ws = (float*)d_ws;
  // layout (float units):
  // proj (bf16, 19,968,000 el)   : [0, 9,984,000)
  // biasP(fp32, 4*325*352)       : [9,984,000, 10,441,600)
  // val  (bf16, 3,993,600 el)    : [10,441,600, 12,438,400)
  // vT   (bf16, 4,325,376 el)    : [12,438,400, 14,601,088)
  // Wcat (bf16, 28,672 el)       : [14,601,088, 14,615,424)
  // bcat (fp32, 320)             : [14,615,424, 14,615,744)
  ushort* proj  = (ushort*)ws;
  float*  biasP = ws + 9984000;
  ushort* val   = (ushort*)(ws + 10441600);
  ushort* vt    = (ushort*)(ws + 12438400);
  ushort* Wcat  = (ushort*)(ws + 14601088);
  float*  bcat  = ws + 14615424;
  ushort* Wf1b  = Wcat + 320*64;
  ushort* Wf2b  = Wcat + 384*64;

  wpack_kernel<<<1, 256, 0, stream>>>(Wq, bq, Wk, bk, Wks, bks,
                                      Wv, bv, Wvs, bvs, Wf1, Wf2, Wcat, bcat);
  bias_kernel<<<(KH*NN*BSTR + 255)/256, 256, 0, stream>>>(Wdi, Wdo, A, AT, biasP);
  proj_kernel<<<975, 256, 0, stream>>>(x, Wcat, bcat, proj);
  vtrans_kernel<<<dim3(BT, KH), 256, 0, stream>>>(proj, vt);
  attn_kernel<<<dim3(21, BT, KH), 256, 0, stream>>>(proj, biasP, vt, val);
  ffn_kernel<<<975, 256, 0, stream>>>(val, x, Wf1b, bf1, Wf2b, bf2,
                                      g_ln, b_ln, out);
}

// Round 5
// 230.087 us; speedup vs baseline: 6.0035x; 1.0210x over previous
//
#include <hip/hip_runtime.h>
#include <math.h>

#define NN 325
#define FD 64
#define KH 4
#define DH 16
#define BT 192
#define NN2 (NN*NN)
#define PST (NN*DH)     // 5200 elems per (proj,head,bt) slice
#define SSTR 340        // attn S row stride (dwords)
#define BSTR 352        // padded bias row stride (floats)
#define VTS  352        // vT row stride (bf16)
#define VSLICE (16*VTS) // vT per-(h,bt) slice
#define VLP  360        // vtrans LDS stride (bf16)
#define HSTR 72         // ffn LDS transpose stride (bf16)
#define NBIAS ((KH*NN*BSTR + 255)/256)   // bias blocks = 1788

typedef __attribute__((ext_vector_type(8))) short short8;
typedef __attribute__((ext_vector_type(4))) float f32x4;

union U8 { uint4 u; short8 s; ushort us[8]; };
__device__ inline short8 lds8(const ushort* p){ U8 t; t.u = *(const uint4*)p; return t.s; }
__device__ inline float b2f(ushort v){ return __uint_as_float(((unsigned)v) << 16); }
__device__ inline ushort f2b(float f){
  unsigned u = __float_as_uint(f);
  u += 0x7fff + ((u >> 16) & 1);
  return (ushort)(u >> 16);
}
__device__ inline short8 cvt8(const float* p){
  float4 u = ((const float4*)p)[0], v = ((const float4*)p)[1];
  U8 t;
  t.us[0]=f2b(u.x); t.us[1]=f2b(u.y); t.us[2]=f2b(u.z); t.us[3]=f2b(u.w);
  t.us[4]=f2b(v.x); t.us[5]=f2b(v.y); t.us[6]=f2b(v.z); t.us[7]=f2b(v.w);
  return t.s;
}

// ---------------- bias padded [4][325][352] (pad=-1e30) + wpack in tail blocks ----------------
__global__ __launch_bounds__(256) void bias_kernel(
    const float* __restrict__ Wdi, const float* __restrict__ Wdo,
    const float* __restrict__ A,   const float* __restrict__ AT,
    float* __restrict__ biasP,
    const float* __restrict__ Wq,  const float* __restrict__ bq,
    const float* __restrict__ Wk,  const float* __restrict__ bk,
    const float* __restrict__ Wks, const float* __restrict__ bks,
    const float* __restrict__ Wv,  const float* __restrict__ bv,
    const float* __restrict__ Wvs, const float* __restrict__ bvs,
    const float* __restrict__ Wf1, const float* __restrict__ Wf2,
    ushort* __restrict__ Wcat, float* __restrict__ bcat){
  if (blockIdx.x >= NBIAS){
    // wpack: 7 blocks, 64 rows each
    int blk = blockIdx.x - NBIAS;
    const float* Ws[7] = {Wq, Wk, Wks, Wv, Wvs, Wf1, Wf2};
    const float* bs[5] = {bq, bk, bks, bv, bvs};
    int f = blk * 64 + (threadIdx.x >> 2);      // 4 threads per row
    int c0 = (threadIdx.x & 3) * 8;
    const float* wr = Ws[blk] + (f & 63) * 64;
    unsigned* dst = (unsigned*)Wcat + f * 32 + c0;
    #pragma unroll
    for (int c = 0; c < 8; ++c)
      dst[c] = f2b(wr[2*(c0+c)]) | ((unsigned)f2b(wr[2*(c0+c)+1]) << 16);
    if (blk < 5 && (threadIdx.x & 3) == 0) bcat[f] = bs[blk][f & 63];
    return;
  }
  int idx = blockIdx.x * 256 + threadIdx.x;
  if (idx >= KH * NN * BSTR) return;
  int h = idx / (NN * BSTR), rem = idx - h * (NN * BSTR);
  int n = rem / BSTR, m = rem - n * BSTR;
  float s = -1e30f;
  if (m < NN){
    int r = n * NN + m;
    s = 0.f;
    if (h < 2){
      #pragma unroll
      for (int k = 0; k < 3; ++k) s += Wdi[(h*3 + k)*NN2 + r] * A[k*NN2 + r];
    } else {
      int h2 = h - 2;
      #pragma unroll
      for (int k = 0; k < 3; ++k) s += Wdo[(h2*3 + k)*NN2 + r] * AT[k*NN2 + r];
    }
  }
  biasP[idx] = s;
}

// ---------------- projections via MFMA; Q pre-scaled by 0.25 ----------------
__global__ __launch_bounds__(256) void proj_kernel(
    const float* __restrict__ x, const ushort* __restrict__ Wcat,
    const float* __restrict__ bcat, ushort* __restrict__ proj){
  int tid = threadIdx.x, lane = tid & 63, wid = tid >> 6;
  int r0 = blockIdx.x * 64 + wid * 16;
  int m = lane & 15, kc = lane >> 4;
  const float* xr = x + (size_t)(r0 + m) * 64 + kc * 8;
  short8 a0 = cvt8(xr);
  short8 a1 = cvt8(xr + 32);
  int btA[4], nA[4];
  #pragma unroll
  for (int rg = 0; rg < 4; ++rg){
    int gr = r0 + kc * 4 + rg;
    btA[rg] = gr / NN; nA[rg] = gr - btA[rg] * NN;
  }
  for (int ct = 0; ct < 20; ++ct){
    short8 b0 = lds8(Wcat + ((size_t)(ct*16 + m) * 64 + kc * 8));
    short8 b1 = lds8(Wcat + ((size_t)(ct*16 + m) * 64 + kc * 8 + 32));
    float bv = bcat[ct*16 + m];
    f32x4 acc = {bv, bv, bv, bv};
    acc = __builtin_amdgcn_mfma_f32_16x16x32_bf16(a0, b0, acc, 0, 0, 0);
    acc = __builtin_amdgcn_mfma_f32_16x16x32_bf16(a1, b1, acc, 0, 0, 0);
    float sc = (ct < 4) ? 0.25f : 1.0f;   // fold 1/sqrt(D) into Q
    #pragma unroll
    for (int rg = 0; rg < 4; ++rg){
      size_t addr = ((size_t)ct * BT + btA[rg]) * PST + nA[rg] * 16 + m;
      proj[addr] = f2b(acc[rg] * sc);
    }
  }
}

// ---------------- V transpose via LDS: coalesced writes ----------------
__global__ __launch_bounds__(256) void vtrans_kernel(
    const ushort* __restrict__ proj, ushort* __restrict__ vt){
  __shared__ ushort t[16 * VLP];
  int bt = blockIdx.x, h = blockIdx.y, tid = threadIdx.x;
  const ushort* vb = proj + (size_t)((3*KH + h)*BT + bt) * PST;
  for (int i = tid; i < 16*27; i += 256)
    t[(i/27)*VLP + NN + (i%27)] = 0;
  for (int i = tid; i < 650; i += 256){
    U8 u; u.u = ((const uint4*)vb)[i];
    int n = i >> 1, dd = (i & 1) * 8;
    #pragma unroll
    for (int j = 0; j < 8; ++j) t[(dd+j)*VLP + n] = u.us[j];
  }
  __syncthreads();
  uint4* outp = (uint4*)(vt + (size_t)(h*BT + bt) * VSLICE);
  for (int i = tid; i < 704; i += 256){
    int d = i / 44, c = (i % 44) * 8;
    outp[i] = *(const uint4*)&t[d*VLP + c];
  }
}

// ---------------- attention: block per (qt,bt,h); P stays in registers ----------------
__global__ __launch_bounds__(256, 4) void attn_kernel(
    const ushort* __restrict__ proj, const float* __restrict__ biasP,
    const ushort* __restrict__ vt, ushort* __restrict__ val){
  __shared__ float S[16 * SSTR];
  __shared__ float part[4][16][16];
  __shared__ float sums[4][16];
  int qt = blockIdx.x, bt = blockIdx.y, h = blockIdx.z;
  int tid = threadIdx.x, lane = tid & 63, wid = tid >> 6;
  const ushort* qb  = proj + (size_t)((0*KH + h)*BT + bt) * PST;
  const ushort* kb  = proj + (size_t)((1*KH + h)*BT + bt) * PST;
  const ushort* ksb = proj + (size_t)((2*KH + h)*BT + bt) * PST;
  const ushort* vsb = proj + (size_t)((4*KH + h)*BT + bt) * PST;
  const ushort* vtg = vt + (size_t)(h*BT + bt) * VSLICE;

  int m = lane & 15, g = lane >> 4;
  short8 zero = {0,0,0,0,0,0,0,0};

  // ---- S = Q' K^T (Q pre-scaled): 21 col-tiles split across waves ----
  {
    short8 aq = (g < 2) ? lds8(qb + ((size_t)(qt*16 + m) * 16 + g * 8)) : zero;
    for (int ct = wid; ct < 21; ct += 4){
      short8 bk = (g < 2) ? lds8(kb + ((size_t)(ct*16 + m) * 16 + g * 8)) : zero;
      f32x4 acc = {0.f, 0.f, 0.f, 0.f};
      acc = __builtin_amdgcn_mfma_f32_16x16x32_bf16(aq, bk, acc, 0, 0, 0);
      #pragma unroll
      for (int rg = 0; rg < 4; ++rg)
        S[(g*4 + rg)*SSTR + ct*16 + m] = acc[rg];
    }
  }
  __syncthreads();

  // ---- softmax in A-fragment layout (no max-sub; scores tiny) + PV ----
  {
    int nb = min(qt*16 + m, NN - 1);
    const float* bp = biasP + (size_t)(h*NN + nb) * BSTR;
    const float* sr = S + m * SSTR;
    float sum = 0.f;
    f32x4 acc = {0.f, 0.f, 0.f, 0.f};
    #pragma unroll
    for (int i = 0; i < 3; ++i){
      int tt = wid + 4*i;
      if (tt > 10) break;
      int c0 = tt*32 + g*8;
      short8 P = zero;
      if (!(tt == 10 && g >= 2)){
        float4 s0 = *(const float4*)(sr + c0);
        float4 s1 = *(const float4*)(sr + c0 + 4);
        float4 b0 = *(const float4*)(bp + c0);
        float4 b1 = *(const float4*)(bp + c0 + 4);
        float e0 = __expf(s0.x + b0.x), e1 = __expf(s0.y + b0.y);
        float e2 = __expf(s0.z + b0.z), e3 = __expf(s0.w + b0.w);
        float e4 = __expf(s1.x + b1.x), e5 = __expf(s1.y + b1.y);
        float e6 = __expf(s1.z + b1.z), e7 = __expf(s1.w + b1.w);
        sum += (e0+e1) + (e2+e3) + (e4+e5) + (e6+e7);
        U8 t;
        t.us[0]=f2b(e0); t.us[1]=f2b(e1); t.us[2]=f2b(e2); t.us[3]=f2b(e3);
        t.us[4]=f2b(e4); t.us[5]=f2b(e5); t.us[6]=f2b(e6); t.us[7]=f2b(e7);
        P = t.s;
      }
      short8 bv = lds8(vtg + (size_t)m * VTS + c0);
      acc = __builtin_amdgcn_mfma_f32_16x16x32_bf16(P, bv, acc, 0, 0, 0);
    }
    #pragma unroll
    for (int rg = 0; rg < 4; ++rg)
      part[wid][g*4 + rg][m] = acc[rg];
    sum += __shfl_xor(sum, 16, 64);
    sum += __shfl_xor(sum, 32, 64);
    if (g == 0) sums[wid][m] = sum;
  }
  __syncthreads();

  // ---- epilogue: 256 threads, one (row,d) each ----
  {
    int r = tid >> 4, d = tid & 15;
    int ng = qt * 16 + r;
    if (ng < NN){
      float s = part[0][r][d] + part[1][r][d] + part[2][r][d] + part[3][r][d];
      float total = sums[0][r] + sums[1][r] + sums[2][r] + sums[3][r];
      float dp = b2f(qb[(size_t)ng * 16 + d]) * b2f(ksb[(size_t)ng * 16 + d]);
      dp += __shfl_xor(dp, 1, 64); dp += __shfl_xor(dp, 2, 64);
      dp += __shfl_xor(dp, 4, 64); dp += __shfl_xor(dp, 8, 64);
      float esv = 1.f / (1.f + __expf(-dp));       // q pre-scaled by 0.25
      float iv = 1.f / (esv + total);
      float res = s * iv + (1.f - total * iv) * b2f(vsb[(size_t)ng * 16 + d]);
      val[((size_t)bt * NN + ng) * FD + h * 16 + d] = f2b(res);
    }
  }
}

// ---------------- FFN + residual + LayerNorm via MFMA ----------------
__global__ __launch_bounds__(256) void ffn_kernel(
    const ushort* __restrict__ val, const float* __restrict__ x,
    const ushort* __restrict__ Wf1b, const float* __restrict__ bf1,
    const ushort* __restrict__ Wf2b, const float* __restrict__ bf2,
    const float* __restrict__ g_ln, const float* __restrict__ b_ln,
    float* __restrict__ out){
  __shared__ ushort hs[4][16 * HSTR];
  int tid = threadIdx.x, lane = tid & 63, wid = tid >> 6;
  int m = lane & 15, kc = lane >> 4;
  int r0 = blockIdx.x * 64 + wid * 16;

  short8 a0 = lds8(val + ((size_t)(r0 + m) * 64 + kc * 8));
  short8 a1 = lds8(val + ((size_t)(r0 + m) * 64 + kc * 8 + 32));
  f32x4 acc1[4];
  #pragma unroll
  for (int ct = 0; ct < 4; ++ct){
    short8 b0 = lds8(Wf1b + ((size_t)(ct*16 + m) * 64 + kc * 8));
    short8 b1 = lds8(Wf1b + ((size_t)(ct*16 + m) * 64 + kc * 8 + 32));
    float bv = bf1[ct*16 + m];
    f32x4 acc = {bv, bv, bv, bv};
    acc = __builtin_amdgcn_mfma_f32_16x16x32_bf16(a0, b0, acc, 0, 0, 0);
    acc1[ct] = __builtin_amdgcn_mfma_f32_16x16x32_bf16(a1, b1, acc, 0, 0, 0);
  }
  #pragma unroll
  for (int ct = 0; ct < 4; ++ct){
    #pragma unroll
    for (int rg = 0; rg < 4; ++rg){
      float t = acc1[ct][rg];
      float gv = 0.5f * t * (1.f + erff(t * 0.70710678118654752f));
      hs[wid][(kc*4 + rg) * HSTR + ct*16 + m] = f2b(gv);
    }
  }
  __syncthreads();
  short8 h0 = lds8(&hs[wid][m * HSTR + kc * 8]);
  short8 h1 = lds8(&hs[wid][m * HSTR + kc * 8 + 32]);

  f32x4 acc2[4];
  #pragma unroll
  for (int ct = 0; ct < 4; ++ct){
    short8 b0 = lds8(Wf2b + ((size_t)(ct*16 + m) * 64 + kc * 8));
    short8 b1 = lds8(Wf2b + ((size_t)(ct*16 + m) * 64 + kc * 8 + 32));
    float bv = bf2[ct*16 + m];
    f32x4 acc = {bv, bv, bv, bv};
    acc = __builtin_amdgcn_mfma_f32_16x16x32_bf16(h0, b0, acc, 0, 0, 0);
    acc2[ct] = __builtin_amdgcn_mfma_f32_16x16x32_bf16(h1, b1, acc, 0, 0, 0);
  }
  float t[4][4];
  #pragma unroll
  for (int ct = 0; ct < 4; ++ct){
    #pragma unroll
    for (int rg = 0; rg < 4; ++rg)
      t[ct][rg] = acc2[ct][rg] + x[(size_t)(r0 + kc*4 + rg) * 64 + ct*16 + m];
  }
  float mu[4], rs[4];
  #pragma unroll
  for (int rg = 0; rg < 4; ++rg){
    float s = t[0][rg] + t[1][rg] + t[2][rg] + t[3][rg];
    s += __shfl_xor(s, 1, 64); s += __shfl_xor(s, 2, 64);
    s += __shfl_xor(s, 4, 64); s += __shfl_xor(s, 8, 64);
    mu[rg] = s * (1.f/64.f);
  }
  #pragma unroll
  for (int rg = 0; rg < 4; ++rg){
    float d0 = t[0][rg]-mu[rg], d1 = t[1][rg]-mu[rg];
    float d2 = t[2][rg]-mu[rg], d3 = t[3][rg]-mu[rg];
    float s = d0*d0 + d1*d1 + d2*d2 + d3*d3;
    s += __shfl_xor(s, 1, 64); s += __shfl_xor(s, 2, 64);
    s += __shfl_xor(s, 4, 64); s += __shfl_xor(s, 8, 64);
    rs[rg] = rsqrtf(s * (1.f/64.f) + 1e-5f);
  }
  #pragma unroll
  for (int ct = 0; ct < 4; ++ct){
    float g = g_ln[ct*16 + m], b = b_ln[ct*16 + m];
    #pragma unroll
    for (int rg = 0; rg < 4; ++rg)
      out[(size_t)(r0 + kc*4 + rg) * 64 + ct*16 + m] =
          g * (t[ct][rg] - mu[rg]) * rs[rg] + b;
  }
}

extern "C" void kernel_launch(void* const* d_in, const int* in_sizes, int n_in,
                              void* d_out, int out_size, void* d_ws, size_t ws_size,
                              hipStream_t stream) {
  const float* x    = (const float*)d_in[0];
  const float* A    = (const float*)d_in[1];
  const float* AT   = (const float*)d_in[2];
  const float* Wq   = (const float*)d_in[3];
  const float* bq   = (const float*)d_in[4];
  const float* Wk   = (const float*)d_in[5];
  const float* bk   = (const float*)d_in[6];
  const float* Wks  = (const float*)d_in[7];
  const float* bks  = (const float*)d_in[8];
  const float* Wv   = (const float*)d_in[9];
  const float* bv   = (const float*)d_in[10];
  const float* Wvs  = (const float*)d_in[11];
  const float* bvs  = (const float*)d_in[12];
  const float* Wdi  = (const float*)d_in[13];
  const float* Wdo  = (const float*)d_in[14];
  const float* Wf1  = (const float*)d_in[15];
  const float* bf1  = (const float*)d_in[16];
  const float* Wf2  = (const float*)d_in[17];
  const float* bf2  = (const float*)d_in[18];
  const float* g_ln = (const float*)d_in[19];
  const float* b_ln = (const float*)d_in[20];
  float* out = (float*)d_out;

  float* ws = (float*)d_ws;
  ushort* proj  = (ushort*)ws;                     // bf16, 19,968,000 el
  float*  biasP = ws + 9984000;                    // fp32, 457,600
  ushort* val   = (ushort*)(ws + 10441600);        // bf16, 3,993,600 el
  ushort* vt    = (ushort*)(ws + 12438400);        // bf16, 4,325,376 el
  ushort* Wcat  = (ushort*)(ws + 14601088);        // bf16, 28,672 el
  float*  bcat  = ws + 14615424;                   // fp32, 320
  ushort* Wf1b  = Wcat + 320*64;
  ushort* Wf2b  = Wcat + 384*64;

  bias_kernel<<<NBIAS + 7, 256, 0, stream>>>(Wdi, Wdo, A, AT, biasP,
                                             Wq, bq, Wk, bk, Wks, bks,
                                             Wv, bv, Wvs, bvs, Wf1, Wf2,
                                             Wcat, bcat);
  proj_kernel<<<975, 256, 0, stream>>>(x, Wcat, bcat, proj);
  vtrans_kernel<<<dim3(BT, KH), 256, 0, stream>>>(proj, vt);
  attn_kernel<<<dim3(21, BT, KH), 256, 0, stream>>>(proj, biasP, vt, val);
  ffn_kernel<<<975, 256, 0, stream>>>(val, x, Wf1b, bf1, Wf2b, bf2,
                                      g_ln, b_ln, out);
}

// Round 6
// 223.026 us; speedup vs baseline: 6.1935x; 1.0317x over previous
//
#include <hip/hip_runtime.h>
#include <hip/hip_bf16.h>
#include <math.h>

#define NN 325
#define FD 64
#define KH 4
#define DH 16
#define BT 192
#define NN2 (NN*NN)
#define PST (NN*DH)     // 5200 elems per (proj,head,bt) slice
#define SSTR 340        // attn S row stride (dwords)
#define BSTR 352        // padded bias row stride (floats)
#define VTS  352        // vT row stride (bf16)
#define VSLICE (16*VTS) // vT per-(h,bt) slice
#define VLP  360        // vtrans LDS stride (bf16)
#define HSTR 72         // ffn LDS stride (bf16)
#define NBIAS ((KH*NN*BSTR + 255)/256)   // bias blocks = 1788

typedef __attribute__((ext_vector_type(8))) short short8;
typedef __attribute__((ext_vector_type(4))) float f32x4;

union U8 { uint4 u; short8 s; ushort us[8]; };
__device__ inline short8 lds8(const ushort* p){ U8 t; t.u = *(const uint4*)p; return t.s; }
__device__ inline float b2f(ushort v){ return __uint_as_float(((unsigned)v) << 16); }
__device__ inline ushort f2b(float f){
  unsigned u = __float_as_uint(f);
  u += 0x7fff + ((u >> 16) & 1);
  return (ushort)(u >> 16);
}
__device__ inline unsigned pk2(float a, float b){
  union { __hip_bfloat162 h; unsigned u; } t;
  t.h = __float22bfloat162_rn(float2{a, b});
  return t.u;
}
__device__ inline short8 cvt8(const float* p){
  float4 u = ((const float4*)p)[0], v = ((const float4*)p)[1];
  U8 t;
  t.us[0]=f2b(u.x); t.us[1]=f2b(u.y); t.us[2]=f2b(u.z); t.us[3]=f2b(u.w);
  t.us[4]=f2b(v.x); t.us[5]=f2b(v.y); t.us[6]=f2b(v.z); t.us[7]=f2b(v.w);
  return t.s;
}

// ---------------- bias padded [4][325][352] (pad=-1e30) + wpack tail blocks ----------------
__global__ __launch_bounds__(256) void bias_kernel(
    const float* __restrict__ Wdi, const float* __restrict__ Wdo,
    const float* __restrict__ A,   const float* __restrict__ AT,
    float* __restrict__ biasP,
    const float* __restrict__ Wq,  const float* __restrict__ bq,
    const float* __restrict__ Wk,  const float* __restrict__ bk,
    const float* __restrict__ Wks, const float* __restrict__ bks,
    const float* __restrict__ Wv,  const float* __restrict__ bv,
    const float* __restrict__ Wvs, const float* __restrict__ bvs,
    const float* __restrict__ Wf1, const float* __restrict__ Wf2,
    ushort* __restrict__ Wcat, float* __restrict__ bcat){
  if (blockIdx.x >= NBIAS){
    int blk = blockIdx.x - NBIAS;
    const float* Ws[7] = {Wq, Wk, Wks, Wv, Wvs, Wf1, Wf2};
    const float* bs[5] = {bq, bk, bks, bv, bvs};
    int f = blk * 64 + (threadIdx.x >> 2);
    int c0 = (threadIdx.x & 3) * 8;
    const float* wr = Ws[blk] + (f & 63) * 64;
    unsigned* dst = (unsigned*)Wcat + f * 32 + c0;
    #pragma unroll
    for (int c = 0; c < 8; ++c)
      dst[c] = f2b(wr[2*(c0+c)]) | ((unsigned)f2b(wr[2*(c0+c)+1]) << 16);
    if (blk < 5 && (threadIdx.x & 3) == 0) bcat[f] = bs[blk][f & 63];
    return;
  }
  int idx = blockIdx.x * 256 + threadIdx.x;
  if (idx >= KH * NN * BSTR) return;
  int h = idx / (NN * BSTR), rem = idx - h * (NN * BSTR);
  int n = rem / BSTR, m = rem - n * BSTR;
  float s = -1e30f;
  if (m < NN){
    int r = n * NN + m;
    s = 0.f;
    if (h < 2){
      #pragma unroll
      for (int k = 0; k < 3; ++k) s += Wdi[(h*3 + k)*NN2 + r] * A[k*NN2 + r];
    } else {
      int h2 = h - 2;
      #pragma unroll
      for (int k = 0; k < 3; ++k) s += Wdo[(h2*3 + k)*NN2 + r] * AT[k*NN2 + r];
    }
  }
  biasP[idx] = s;
}

// ---------------- projections: A=W rows, B=x rows -> vectorized stores ----------------
__global__ __launch_bounds__(256) void proj_kernel(
    const float* __restrict__ x, const ushort* __restrict__ Wcat,
    const float* __restrict__ bcat, ushort* __restrict__ proj){
  int tid = threadIdx.x, lane = tid & 63, wid = tid >> 6;
  int r0 = blockIdx.x * 64 + wid * 16;
  int m = lane & 15, g = lane >> 4;
  int gr = r0 + m;                        // this lane's x row (D col)
  int bt = gr / NN, n = gr - bt * NN;
  const float* xr = x + (size_t)gr * 64 + g * 8;
  short8 xb0 = cvt8(xr);
  short8 xb1 = cvt8(xr + 32);
  for (int ct = 0; ct < 20; ++ct){
    short8 w0 = lds8(Wcat + ((size_t)(ct*16 + m) * 64 + g * 8));
    short8 w1 = lds8(Wcat + ((size_t)(ct*16 + m) * 64 + g * 8 + 32));
    float4 b4 = *(const float4*)(bcat + ct*16 + 4*g);
    f32x4 acc = {b4.x, b4.y, b4.z, b4.w};
    acc = __builtin_amdgcn_mfma_f32_16x16x32_bf16(w0, xb0, acc, 0, 0, 0);
    acc = __builtin_amdgcn_mfma_f32_16x16x32_bf16(w1, xb1, acc, 0, 0, 0);
    float sc = (ct < 4) ? 0.25f : 1.0f;   // fold 1/sqrt(D) into Q
    uint2 w;
    w.x = pk2(acc[0]*sc, acc[1]*sc);
    w.y = pk2(acc[2]*sc, acc[3]*sc);
    *(uint2*)(proj + ((size_t)ct * BT + bt) * PST + n*16 + 4*g) = w;
  }
}

// ---------------- V transpose via LDS: coalesced writes ----------------
__global__ __launch_bounds__(256) void vtrans_kernel(
    const ushort* __restrict__ proj, ushort* __restrict__ vt){
  __shared__ ushort t[16 * VLP];
  int bt = blockIdx.x, h = blockIdx.y, tid = threadIdx.x;
  const ushort* vb = proj + (size_t)((3*KH + h)*BT + bt) * PST;
  for (int i = tid; i < 16*27; i += 256)
    t[(i/27)*VLP + NN + (i%27)] = 0;
  for (int i = tid; i < 650; i += 256){
    U8 u; u.u = ((const uint4*)vb)[i];
    int n = i >> 1, dd = (i & 1) * 8;
    #pragma unroll
    for (int j = 0; j < 8; ++j) t[(dd+j)*VLP + n] = u.us[j];
  }
  __syncthreads();
  uint4* outp = (uint4*)(vt + (size_t)(h*BT + bt) * VSLICE);
  for (int i = tid; i < 704; i += 256){
    int d = i / 44, c = (i % 44) * 8;
    outp[i] = *(const uint4*)&t[d*VLP + c];
  }
}

// ---------------- attention: block per (qt,bt,h) ----------------
__global__ __launch_bounds__(256, 4) void attn_kernel(
    const ushort* __restrict__ proj, const float* __restrict__ biasP,
    const ushort* __restrict__ vt, ushort* __restrict__ val){
  __shared__ float S[16 * SSTR];       // fp32 scores; P in-place bf16
  __shared__ float part[4][16][16];
  __shared__ float rstat[16][2];
  int qt = blockIdx.x, bt = blockIdx.y, h = blockIdx.z;
  int tid = threadIdx.x, lane = tid & 63, wid = tid >> 6;
  const ushort* qb  = proj + (size_t)((0*KH + h)*BT + bt) * PST;
  const ushort* kb  = proj + (size_t)((1*KH + h)*BT + bt) * PST;
  const ushort* ksb = proj + (size_t)((2*KH + h)*BT + bt) * PST;
  const ushort* vsb = proj + (size_t)((4*KH + h)*BT + bt) * PST;
  const ushort* vtg = vt + (size_t)(h*BT + bt) * VSLICE;

  int m = lane & 15, g = lane >> 4;
  short8 zero = {0,0,0,0,0,0,0,0};

  // ---- phase 1: S = Q' K^T (Q pre-scaled), col-tiles split across waves ----
  {
    short8 aq = (g < 2) ? lds8(qb + ((size_t)(qt*16 + m) * 16 + g * 8)) : zero;
    for (int ct = wid; ct < 21; ct += 4){
      short8 bk = (g < 2) ? lds8(kb + ((size_t)(ct*16 + m) * 16 + g * 8)) : zero;
      f32x4 acc = {0.f, 0.f, 0.f, 0.f};
      acc = __builtin_amdgcn_mfma_f32_16x16x32_bf16(aq, bk, acc, 0, 0, 0);
      #pragma unroll
      for (int rg = 0; rg < 4; ++rg)
        S[(g*4 + rg)*SSTR + ct*16 + m] = acc[rg];
    }
  }
  __syncthreads();

  // ---- phase 2: softmax (coalesced; no max-sub, scores tiny; bias pad kills tail) ----
  {
    int r = tid >> 4, c = tid & 15;
    int n = qt * 16 + r;
    int nb = min(n, NN - 1);
    const float* bp = biasP + (size_t)(h*NN + nb) * BSTR;
    float* sr = S + r * SSTR;
    float4 e[6];
    float sum = 0.f;
    #pragma unroll
    for (int j = 0; j < 6; ++j){
      int m0 = c * 4 + 64 * j;
      if (m0 < 336){
        float4 s4 = *(const float4*)(sr + m0);
        float4 b4 = *(const float4*)(bp + m0);
        float4 t;
        t.x = __expf(s4.x + b4.x); t.y = __expf(s4.y + b4.y);
        t.z = __expf(s4.z + b4.z); t.w = __expf(s4.w + b4.w);
        sum += (t.x + t.y) + (t.z + t.w);
        e[j] = t;
      } else {
        e[j] = make_float4(0.f, 0.f, 0.f, 0.f);
      }
    }
    // sigmoid term (lane c = dim d)
    float dp = b2f(qb[(size_t)nb * 16 + c]) * b2f(ksb[(size_t)nb * 16 + c]);
    dp += __shfl_xor(dp, 1, 64); dp += __shfl_xor(dp, 2, 64);
    dp += __shfl_xor(dp, 4, 64); dp += __shfl_xor(dp, 8, 64);
    sum += __shfl_xor(sum, 1, 64); sum += __shfl_xor(sum, 2, 64);
    sum += __shfl_xor(sum, 4, 64); sum += __shfl_xor(sum, 8, 64);
    if (c == 0){
      float esv = 1.f / (1.f + __expf(-dp));   // q pre-scaled by 0.25
      float iv = 1.f / (esv + sum);
      rstat[r][0] = iv; rstat[r][1] = 1.f - sum * iv;
    }
    // all S reads (this row, owned by this wave) done; now pack P in place.
    asm volatile("" ::: "memory");
    ushort* pr = (ushort*)sr;
    #pragma unroll
    for (int j = 0; j < 6; ++j){
      int m0 = c * 4 + 64 * j;
      if (m0 < 336){
        uint2 w;
        w.x = pk2(e[j].x, e[j].y);
        w.y = pk2(e[j].z, e[j].w);
        *(uint2*)(pr + m0) = w;
      }
    }
  }
  __syncthreads();

  // ---- phase 3: PV, K-steps split across waves ----
  {
    const ushort* prow = (const ushort*)S + (size_t)m * (SSTR * 2);
    f32x4 acc = {0.f, 0.f, 0.f, 0.f};
    for (int tt = wid; tt < 11; tt += 4){
      short8 ap = (tt == 10 && g >= 2) ? zero : lds8(prow + tt*32 + g*8);
      short8 bv = lds8(vtg + (size_t)m * VTS + tt*32 + g*8);
      acc = __builtin_amdgcn_mfma_f32_16x16x32_bf16(ap, bv, acc, 0, 0, 0);
    }
    #pragma unroll
    for (int rg = 0; rg < 4; ++rg)
      part[wid][g*4 + rg][m] = acc[rg];
  }
  __syncthreads();

  // ---- epilogue ----
  {
    int r = tid >> 4, d = tid & 15;
    int ng = qt * 16 + r;
    if (ng < NN){
      float s = part[0][r][d] + part[1][r][d] + part[2][r][d] + part[3][r][d];
      float res = s * rstat[r][0] + rstat[r][1] * b2f(vsb[(size_t)ng * 16 + d]);
      val[((size_t)bt * NN + ng) * FD + h * 16 + d] = f2b(res);
    }
  }
}

// ---------------- FFN + residual + LayerNorm (swapped operands) ----------------
__global__ __launch_bounds__(256) void ffn_kernel(
    const ushort* __restrict__ val, const float* __restrict__ x,
    const ushort* __restrict__ Wf1b, const float* __restrict__ bf1,
    const ushort* __restrict__ Wf2b, const float* __restrict__ bf2,
    const float* __restrict__ g_ln, const float* __restrict__ b_ln,
    float* __restrict__ out){
  __shared__ ushort hs[4][16 * HSTR];
  int tid = threadIdx.x, lane = tid & 63, wid = tid >> 6;
  int m = lane & 15, g = lane >> 4;
  int r0 = blockIdx.x * 64 + wid * 16;
  int row = r0 + m;                       // this lane's x row (D col)

  // B operand: val rows
  short8 vb0 = lds8(val + ((size_t)row * 64 + g * 8));
  short8 vb1 = lds8(val + ((size_t)row * 64 + g * 8 + 32));

  // GEMM1: rows = hidden features
  #pragma unroll
  for (int ct = 0; ct < 4; ++ct){
    short8 w0 = lds8(Wf1b + ((size_t)(ct*16 + m) * 64 + g * 8));
    short8 w1 = lds8(Wf1b + ((size_t)(ct*16 + m) * 64 + g * 8 + 32));
    float4 b4 = *(const float4*)(bf1 + ct*16 + 4*g);
    f32x4 acc = {b4.x, b4.y, b4.z, b4.w};
    acc = __builtin_amdgcn_mfma_f32_16x16x32_bf16(w0, vb0, acc, 0, 0, 0);
    acc = __builtin_amdgcn_mfma_f32_16x16x32_bf16(w1, vb1, acc, 0, 0, 0);
    uint2 w;
    float g0 = 0.5f*acc[0]*(1.f + erff(acc[0]*0.70710678118654752f));
    float g1 = 0.5f*acc[1]*(1.f + erff(acc[1]*0.70710678118654752f));
    float g2 = 0.5f*acc[2]*(1.f + erff(acc[2]*0.70710678118654752f));
    float g3 = 0.5f*acc[3]*(1.f + erff(acc[3]*0.70710678118654752f));
    w.x = pk2(g0, g1); w.y = pk2(g2, g3);
    *(uint2*)&hs[wid][m * HSTR + ct*16 + 4*g] = w;   // hs[n][f]
  }
  __syncthreads();
  short8 h0 = lds8(&hs[wid][m * HSTR + g * 8]);
  short8 h1 = lds8(&hs[wid][m * HSTR + g * 8 + 32]);

  // GEMM2 + residual
  float t[4][4];
  #pragma unroll
  for (int ct = 0; ct < 4; ++ct){
    short8 w0 = lds8(Wf2b + ((size_t)(ct*16 + m) * 64 + g * 8));
    short8 w1 = lds8(Wf2b + ((size_t)(ct*16 + m) * 64 + g * 8 + 32));
    float4 b4 = *(const float4*)(bf2 + ct*16 + 4*g);
    f32x4 acc = {b4.x, b4.y, b4.z, b4.w};
    acc = __builtin_amdgcn_mfma_f32_16x16x32_bf16(w0, h0, acc, 0, 0, 0);
    acc = __builtin_amdgcn_mfma_f32_16x16x32_bf16(w1, h1, acc, 0, 0, 0);
    float4 xr = *(const float4*)(x + (size_t)row * 64 + ct*16 + 4*g);
    t[ct][0] = acc[0] + xr.x; t[ct][1] = acc[1] + xr.y;
    t[ct][2] = acc[2] + xr.z; t[ct][3] = acc[3] + xr.w;
  }
  // LayerNorm: row = this lane; features spread in-lane(16) x g-groups
  float s = 0.f;
  #pragma unroll
  for (int ct = 0; ct < 4; ++ct) s += (t[ct][0]+t[ct][1]) + (t[ct][2]+t[ct][3]);
  s += __shfl_xor(s, 16, 64); s += __shfl_xor(s, 32, 64);
  float mu = s * (1.f/64.f);
  float v = 0.f;
  #pragma unroll
  for (int ct = 0; ct < 4; ++ct){
    #pragma unroll
    for (int rg = 0; rg < 4; ++rg){ float d = t[ct][rg] - mu; v += d*d; }
  }
  v += __shfl_xor(v, 16, 64); v += __shfl_xor(v, 32, 64);
  float rs = rsqrtf(v * (1.f/64.f) + 1e-5f);
  #pragma unroll
  for (int ct = 0; ct < 4; ++ct){
    float4 g4 = *(const float4*)(g_ln + ct*16 + 4*g);
    float4 bb = *(const float4*)(b_ln + ct*16 + 4*g);
    float4 o;
    o.x = g4.x*(t[ct][0]-mu)*rs + bb.x;
    o.y = g4.y*(t[ct][1]-mu)*rs + bb.y;
    o.z = g4.z*(t[ct][2]-mu)*rs + bb.z;
    o.w = g4.w*(t[ct][3]-mu)*rs + bb.w;
    *(float4*)(out + (size_t)row * 64 + ct*16 + 4*g) = o;
  }
}

extern "C" void kernel_launch(void* const* d_in, const int* in_sizes, int n_in,
                              void* d_out, int out_size, void* d_ws, size_t ws_size,
                              hipStream_t stream) {
  const float* x    = (const float*)d_in[0];
  const float* A    = (const float*)d_in[1];
  const float* AT   = (const float*)d_in[2];
  const float* Wq   = (const float*)d_in[3];
  const float* bq   = (const float*)d_in[4];
  const float* Wk   = (const float*)d_in[5];
  const float* bk   = (const float*)d_in[6];
  const float* Wks  = (const float*)d_in[7];
  const float* bks  = (const float*)d_in[8];
  const float* Wv   = (const float*)d_in[9];
  const float* bv   = (const float*)d_in[10];
  const float* Wvs  = (const float*)d_in[11];
  const float* bvs  = (const float*)d_in[12];
  const float* Wdi  = (const float*)d_in[13];
  const float* Wdo  = (const float*)d_in[14];
  const float* Wf1  = (const float*)d_in[15];
  const float* bf1  = (const float*)d_in[16];
  const float* Wf2  = (const float*)d_in[17];
  const float* bf2  = (const float*)d_in[18];
  const float* g_ln = (const float*)d_in[19];
  const float* b_ln = (const float*)d_in[20];
  float* out = (float*)d_out;

  float* ws = (float*)d_ws;
  ushort* proj  = (ushort*)ws;                     // bf16, 19,968,000 el
  float*  biasP = ws + 9984000;                    // fp32, 457,600
  ushort* val   = (ushort*)(ws + 10441600);        // bf16, 3,993,600 el
  ushort* vt    = (ushort*)(ws + 12438400);        // bf16, 4,325,376 el
  ushort* Wcat  = (ushort*)(ws + 14601088);        // bf16, 28,672 el
  float*  bcat  = ws + 14615424;                   // fp32, 320
  ushort* Wf1b  = Wcat + 320*64;
  ushort* Wf2b  = Wcat + 384*64;

  bias_kernel<<<NBIAS + 7, 256, 0, stream>>>(Wdi, Wdo, A, AT, biasP,
                                             Wq, bq, Wk, bk, Wks, bks,
                                             Wv, bv, Wvs, bvs, Wf1, Wf2,
                                             Wcat, bcat);
  proj_kernel<<<975, 256, 0, stream>>>(x, Wcat, bcat, proj);
  vtrans_kernel<<<dim3(BT, KH), 256, 0, stream>>>(proj, vt);
  attn_kernel<<<dim3(21, BT, KH), 256, 0, stream>>>(proj, biasP, vt, val);
  ffn_kernel<<<975, 256, 0, stream>>>(val, x, Wf1b, bf1, Wf2b, bf2,
                                      g_ln, b_ln, out);
}

// Round 7
// 209.692 us; speedup vs baseline: 6.5874x; 1.0636x over previous
//
#include <hip/hip_runtime.h>
#include <hip/hip_bf16.h>
#include <math.h>

#define NN 325
#define FD 64
#define KH 4
#define DH 16
#define BT 192
#define NN2 (NN*NN)
#define PST (NN*DH)     // 5200 elems per (proj,head,bt) slice
#define SSTR 340        // attn S row stride (dwords)
#define BSTR 352        // padded bias row stride (floats)
#define VTS  352        // vT row stride (bf16)
#define VSLICE (16*VTS) // vT per-(h,bt) slice
#define HSTR 72         // ffn LDS stride (bf16)
#define NPROJ 975
#define NBIAS ((KH*NN*BSTR + 255)/256)   // 1788
#define NPAD  (KH*BT)                    // 768

typedef __attribute__((ext_vector_type(8))) short short8;
typedef __attribute__((ext_vector_type(4))) float f32x4;

union U8 { uint4 u; short8 s; ushort us[8]; };
__device__ inline short8 lds8(const ushort* p){ U8 t; t.u = *(const uint4*)p; return t.s; }
__device__ inline float b2f(ushort v){ return __uint_as_float(((unsigned)v) << 16); }
__device__ inline ushort f2b(float f){
  unsigned u = __float_as_uint(f);
  u += 0x7fff + ((u >> 16) & 1);
  return (ushort)(u >> 16);
}
__device__ inline unsigned pk2(float a, float b){
  union { __hip_bfloat162 h; unsigned u; } t;
  t.h = __float22bfloat162_rn(float2{a, b});
  return t.u;
}
__device__ inline short8 cvt8(const float* p){
  float4 u = ((const float4*)p)[0], v = ((const float4*)p)[1];
  U8 t;
  t.us[0]=f2b(u.x); t.us[1]=f2b(u.y); t.us[2]=f2b(u.z); t.us[3]=f2b(u.w);
  t.us[4]=f2b(v.x); t.us[5]=f2b(v.y); t.us[6]=f2b(v.z); t.us[7]=f2b(v.w);
  return t.s;
}

// ---------------- wpack: W's -> Wcat bf16 [448][64] + bcat ----------------
__global__ __launch_bounds__(256) void wpack_kernel(
    const float* __restrict__ Wq,  const float* __restrict__ bq,
    const float* __restrict__ Wk,  const float* __restrict__ bk,
    const float* __restrict__ Wks, const float* __restrict__ bks,
    const float* __restrict__ Wv,  const float* __restrict__ bv,
    const float* __restrict__ Wvs, const float* __restrict__ bvs,
    const float* __restrict__ Wf1, const float* __restrict__ Wf2,
    ushort* __restrict__ Wcat, float* __restrict__ bcat){
  int blk = blockIdx.x;
  const float* Ws[7] = {Wq, Wk, Wks, Wv, Wvs, Wf1, Wf2};
  const float* bs[5] = {bq, bk, bks, bv, bvs};
  int f = blk * 64 + (threadIdx.x >> 2);
  int c0 = (threadIdx.x & 3) * 8;
  const float* wr = Ws[blk] + (f & 63) * 64;
  unsigned* dst = (unsigned*)Wcat + f * 32 + c0;
  #pragma unroll
  for (int c = 0; c < 8; ++c)
    dst[c] = f2b(wr[2*(c0+c)]) | ((unsigned)f2b(wr[2*(c0+c)+1]) << 16);
  if (blk < 5 && (threadIdx.x & 3) == 0) bcat[f] = bs[blk][f & 63];
}

// ---------------- prep: proj (+V->vt direct) | bias padded | vt pad zero ----------------
__global__ __launch_bounds__(256) void prep_kernel(
    const float* __restrict__ x, const ushort* __restrict__ Wcat,
    const float* __restrict__ bcat, ushort* __restrict__ proj,
    ushort* __restrict__ vt,
    const float* __restrict__ Wdi, const float* __restrict__ Wdo,
    const float* __restrict__ A,   const float* __restrict__ AT,
    float* __restrict__ biasP){
  int bid = blockIdx.x, tid = threadIdx.x;
  if (bid < NPROJ){
    // ---- projections via MFMA (A=W rows, B=x rows) ----
    int lane = tid & 63, wid = tid >> 6;
    int r0 = bid * 64 + wid * 16;
    int m = lane & 15, g = lane >> 4;
    int gr = r0 + m;
    int bt = gr / NN, n = gr - bt * NN;
    const float* xr = x + (size_t)gr * 64 + g * 8;
    short8 xb0 = cvt8(xr);
    short8 xb1 = cvt8(xr + 32);
    for (int ct = 0; ct < 20; ++ct){
      short8 w0 = lds8(Wcat + ((size_t)(ct*16 + m) * 64 + g * 8));
      short8 w1 = lds8(Wcat + ((size_t)(ct*16 + m) * 64 + g * 8 + 32));
      float4 b4 = *(const float4*)(bcat + ct*16 + 4*g);
      f32x4 acc = {b4.x, b4.y, b4.z, b4.w};
      acc = __builtin_amdgcn_mfma_f32_16x16x32_bf16(w0, xb0, acc, 0, 0, 0);
      acc = __builtin_amdgcn_mfma_f32_16x16x32_bf16(w1, xb1, acc, 0, 0, 0);
      if (ct >= 12 && ct < 16){
        // V head (ct-12): write transposed directly to vt[d][n]
        ushort* vs = vt + (size_t)((ct-12)*BT + bt) * VSLICE + n;
        #pragma unroll
        for (int rg = 0; rg < 4; ++rg)
          vs[(size_t)(4*g + rg) * VTS] = f2b(acc[rg]);
      } else {
        float sc = (ct < 4) ? 0.25f : 1.0f;   // fold 1/sqrt(D) into Q
        uint2 w;
        w.x = pk2(acc[0]*sc, acc[1]*sc);
        w.y = pk2(acc[2]*sc, acc[3]*sc);
        *(uint2*)(proj + ((size_t)ct * BT + bt) * PST + n*16 + 4*g) = w;
      }
    }
  } else if (bid < NPROJ + NBIAS){
    // ---- bias padded [4][325][352], pad = -1e30 ----
    int idx = (bid - NPROJ) * 256 + tid;
    if (idx >= KH * NN * BSTR) return;
    int h = idx / (NN * BSTR), rem = idx - h * (NN * BSTR);
    int n = rem / BSTR, m = rem - n * BSTR;
    float s = -1e30f;
    if (m < NN){
      int r = n * NN + m;
      s = 0.f;
      if (h < 2){
        #pragma unroll
        for (int k = 0; k < 3; ++k) s += Wdi[(h*3 + k)*NN2 + r] * A[k*NN2 + r];
      } else {
        int h2 = h - 2;
        #pragma unroll
        for (int k = 0; k < 3; ++k) s += Wdo[(h2*3 + k)*NN2 + r] * AT[k*NN2 + r];
      }
    }
    biasP[idx] = s;
  } else {
    // ---- vt pad: zero cols 325..351 for one (h,bt) slice ----
    int slice = bid - NPROJ - NBIAS;
    ushort* vs = vt + (size_t)slice * VSLICE;
    if (tid < 432){
      int d = tid / 27, c = NN + tid % 27;
      vs[(size_t)d * VTS + c] = 0;
    }
  }
}

// ---------------- attention: block per (bhid, qt); bhid pinned to XCD ----------------
__global__ __launch_bounds__(256, 4) void attn_kernel(
    const ushort* __restrict__ proj, const float* __restrict__ biasP,
    const ushort* __restrict__ vt, ushort* __restrict__ val){
  __shared__ float S[16 * SSTR];       // fp32 scores; P in-place bf16
  __shared__ float part[4][16][16];
  __shared__ float rstat[16][2];
  int bhid = blockIdx.x, qt = blockIdx.y;
  int h = bhid / BT, bt = bhid - h * BT;
  int tid = threadIdx.x, lane = tid & 63, wid = tid >> 6;
  const ushort* qb  = proj + (size_t)((0*KH + h)*BT + bt) * PST;
  const ushort* kb  = proj + (size_t)((1*KH + h)*BT + bt) * PST;
  const ushort* ksb = proj + (size_t)((2*KH + h)*BT + bt) * PST;
  const ushort* vsb = proj + (size_t)((4*KH + h)*BT + bt) * PST;
  const ushort* vtg = vt + (size_t)(h*BT + bt) * VSLICE;

  int m = lane & 15, g = lane >> 4;
  short8 zero = {0,0,0,0,0,0,0,0};

  // ---- phase 1: S = Q' K^T (Q pre-scaled), col-tiles split across waves ----
  {
    short8 aq = (g < 2) ? lds8(qb + ((size_t)(qt*16 + m) * 16 + g * 8)) : zero;
    for (int ct = wid; ct < 21; ct += 4){
      short8 bk = (g < 2) ? lds8(kb + ((size_t)(ct*16 + m) * 16 + g * 8)) : zero;
      f32x4 acc = {0.f, 0.f, 0.f, 0.f};
      acc = __builtin_amdgcn_mfma_f32_16x16x32_bf16(aq, bk, acc, 0, 0, 0);
      #pragma unroll
      for (int rg = 0; rg < 4; ++rg)
        S[(g*4 + rg)*SSTR + ct*16 + m] = acc[rg];
    }
  }
  __syncthreads();

  // ---- phase 2: softmax (coalesced; no max-sub, scores tiny) ----
  {
    int r = tid >> 4, c = tid & 15;
    int n = qt * 16 + r;
    int nb = min(n, NN - 1);
    const float* bp = biasP + (size_t)(h*NN + nb) * BSTR;
    float* sr = S + r * SSTR;
    float4 e[6];
    float sum = 0.f;
    #pragma unroll
    for (int j = 0; j < 6; ++j){
      int m0 = c * 4 + 64 * j;
      if (m0 < 336){
        float4 s4 = *(const float4*)(sr + m0);
        float4 b4 = *(const float4*)(bp + m0);
        float4 t;
        t.x = __expf(s4.x + b4.x); t.y = __expf(s4.y + b4.y);
        t.z = __expf(s4.z + b4.z); t.w = __expf(s4.w + b4.w);
        sum += (t.x + t.y) + (t.z + t.w);
        e[j] = t;
      } else {
        e[j] = make_float4(0.f, 0.f, 0.f, 0.f);
      }
    }
    float dp = b2f(qb[(size_t)nb * 16 + c]) * b2f(ksb[(size_t)nb * 16 + c]);
    dp += __shfl_xor(dp, 1, 64); dp += __shfl_xor(dp, 2, 64);
    dp += __shfl_xor(dp, 4, 64); dp += __shfl_xor(dp, 8, 64);
    sum += __shfl_xor(sum, 1, 64); sum += __shfl_xor(sum, 2, 64);
    sum += __shfl_xor(sum, 4, 64); sum += __shfl_xor(sum, 8, 64);
    if (c == 0){
      float esv = 1.f / (1.f + __expf(-dp));   // q pre-scaled by 0.25
      float iv = 1.f / (esv + sum);
      rstat[r][0] = iv; rstat[r][1] = 1.f - sum * iv;
    }
    asm volatile("" ::: "memory");
    ushort* pr = (ushort*)sr;
    #pragma unroll
    for (int j = 0; j < 6; ++j){
      int m0 = c * 4 + 64 * j;
      if (m0 < 336){
        uint2 w;
        w.x = pk2(e[j].x, e[j].y);
        w.y = pk2(e[j].z, e[j].w);
        *(uint2*)(pr + m0) = w;
      }
    }
  }
  __syncthreads();

  // ---- phase 3: PV, K-steps split across waves ----
  {
    const ushort* prow = (const ushort*)S + (size_t)m * (SSTR * 2);
    f32x4 acc = {0.f, 0.f, 0.f, 0.f};
    for (int tt = wid; tt < 11; tt += 4){
      short8 ap = (tt == 10 && g >= 2) ? zero : lds8(prow + tt*32 + g*8);
      short8 bv = lds8(vtg + (size_t)m * VTS + tt*32 + g*8);
      acc = __builtin_amdgcn_mfma_f32_16x16x32_bf16(ap, bv, acc, 0, 0, 0);
    }
    #pragma unroll
    for (int rg = 0; rg < 4; ++rg)
      part[wid][g*4 + rg][m] = acc[rg];
  }
  __syncthreads();

  // ---- epilogue ----
  {
    int r = tid >> 4, d = tid & 15;
    int ng = qt * 16 + r;
    if (ng < NN){
      float s = part[0][r][d] + part[1][r][d] + part[2][r][d] + part[3][r][d];
      float res = s * rstat[r][0] + rstat[r][1] * b2f(vsb[(size_t)ng * 16 + d]);
      val[((size_t)bt * NN + ng) * FD + h * 16 + d] = f2b(res);
    }
  }
}

// ---------------- FFN + residual + LayerNorm (swapped operands, no barrier) ----------------
__global__ __launch_bounds__(256) void ffn_kernel(
    const ushort* __restrict__ val, const float* __restrict__ x,
    const ushort* __restrict__ Wf1b, const float* __restrict__ bf1,
    const ushort* __restrict__ Wf2b, const float* __restrict__ bf2,
    const float* __restrict__ g_ln, const float* __restrict__ b_ln,
    float* __restrict__ out){
  __shared__ ushort hs[4][16 * HSTR];   // wave-private slices
  int tid = threadIdx.x, lane = tid & 63, wid = tid >> 6;
  int m = lane & 15, g = lane >> 4;
  int r0 = blockIdx.x * 64 + wid * 16;
  int row = r0 + m;

  short8 vb0 = lds8(val + ((size_t)row * 64 + g * 8));
  short8 vb1 = lds8(val + ((size_t)row * 64 + g * 8 + 32));

  #pragma unroll
  for (int ct = 0; ct < 4; ++ct){
    short8 w0 = lds8(Wf1b + ((size_t)(ct*16 + m) * 64 + g * 8));
    short8 w1 = lds8(Wf1b + ((size_t)(ct*16 + m) * 64 + g * 8 + 32));
    float4 b4 = *(const float4*)(bf1 + ct*16 + 4*g);
    f32x4 acc = {b4.x, b4.y, b4.z, b4.w};
    acc = __builtin_amdgcn_mfma_f32_16x16x32_bf16(w0, vb0, acc, 0, 0, 0);
    acc = __builtin_amdgcn_mfma_f32_16x16x32_bf16(w1, vb1, acc, 0, 0, 0);
    uint2 w;
    float g0 = 0.5f*acc[0]*(1.f + erff(acc[0]*0.70710678118654752f));
    float g1 = 0.5f*acc[1]*(1.f + erff(acc[1]*0.70710678118654752f));
    float g2 = 0.5f*acc[2]*(1.f + erff(acc[2]*0.70710678118654752f));
    float g3 = 0.5f*acc[3]*(1.f + erff(acc[3]*0.70710678118654752f));
    w.x = pk2(g0, g1); w.y = pk2(g2, g3);
    *(uint2*)&hs[wid][m * HSTR + ct*16 + 4*g] = w;
  }
  // hs[wid] is wave-private: drain LDS writes, no block barrier needed
  asm volatile("s_waitcnt lgkmcnt(0)" ::: "memory");
  short8 h0 = lds8(&hs[wid][m * HSTR + g * 8]);
  short8 h1 = lds8(&hs[wid][m * HSTR + g * 8 + 32]);

  float t[4][4];
  #pragma unroll
  for (int ct = 0; ct < 4; ++ct){
    short8 w0 = lds8(Wf2b + ((size_t)(ct*16 + m) * 64 + g * 8));
    short8 w1 = lds8(Wf2b + ((size_t)(ct*16 + m) * 64 + g * 8 + 32));
    float4 b4 = *(const float4*)(bf2 + ct*16 + 4*g);
    f32x4 acc = {b4.x, b4.y, b4.z, b4.w};
    acc = __builtin_amdgcn_mfma_f32_16x16x32_bf16(w0, h0, acc, 0, 0, 0);
    acc = __builtin_amdgcn_mfma_f32_16x16x32_bf16(w1, h1, acc, 0, 0, 0);
    float4 xr = *(const float4*)(x + (size_t)row * 64 + ct*16 + 4*g);
    t[ct][0] = acc[0] + xr.x; t[ct][1] = acc[1] + xr.y;
    t[ct][2] = acc[2] + xr.z; t[ct][3] = acc[3] + xr.w;
  }
  float s = 0.f;
  #pragma unroll
  for (int ct = 0; ct < 4; ++ct) s += (t[ct][0]+t[ct][1]) + (t[ct][2]+t[ct][3]);
  s += __shfl_xor(s, 16, 64); s += __shfl_xor(s, 32, 64);
  float mu = s * (1.f/64.f);
  float v = 0.f;
  #pragma unroll
  for (int ct = 0; ct < 4; ++ct){
    #pragma unroll
    for (int rg = 0; rg < 4; ++rg){ float d = t[ct][rg] - mu; v += d*d; }
  }
  v += __shfl_xor(v, 16, 64); v += __shfl_xor(v, 32, 64);
  float rs = rsqrtf(v * (1.f/64.f) + 1e-5f);
  #pragma unroll
  for (int ct = 0; ct < 4; ++ct){
    float4 g4 = *(const float4*)(g_ln + ct*16 + 4*g);
    float4 bb = *(const float4*)(b_ln + ct*16 + 4*g);
    float4 o;
    o.x = g4.x*(t[ct][0]-mu)*rs + bb.x;
    o.y = g4.y*(t[ct][1]-mu)*rs + bb.y;
    o.z = g4.z*(t[ct][2]-mu)*rs + bb.z;
    o.w = g4.w*(t[ct][3]-mu)*rs + bb.w;
    *(float4*)(out + (size_t)row * 64 + ct*16 + 4*g) = o;
  }
}

extern "C" void kernel_launch(void* const* d_in, const int* in_sizes, int n_in,
                              void* d_out, int out_size, void* d_ws, size_t ws_size,
                              hipStream_t stream) {
  const float* x    = (const float*)d_in[0];
  const float* A    = (const float*)d_in[1];
  const float* AT   = (const float*)d_in[2];
  const float* Wq   = (const float*)d_in[3];
  const float* bq   = (const float*)d_in[4];
  const float* Wk   = (const float*)d_in[5];
  const float* bk   = (const float*)d_in[6];
  const float* Wks  = (const float*)d_in[7];
  const float* bks  = (const float*)d_in[8];
  const float* Wv   = (const float*)d_in[9];
  const float* bv   = (const float*)d_in[10];
  const float* Wvs  = (const float*)d_in[11];
  const float* bvs  = (const float*)d_in[12];
  const float* Wdi  = (const float*)d_in[13];
  const float* Wdo  = (const float*)d_in[14];
  const float* Wf1  = (const float*)d_in[15];
  const float* bf1  = (const float*)d_in[16];
  const float* Wf2  = (const float*)d_in[17];
  const float* bf2  = (const float*)d_in[18];
  const float* g_ln = (const float*)d_in[19];
  const float* b_ln = (const float*)d_in[20];
  float* out = (float*)d_out;

  float* ws = (float*)d_ws;
  ushort* proj  = (ushort*)ws;                     // bf16, 19,968,000 el (p=3 unused)
  float*  biasP = ws + 9984000;                    // fp32, 457,600
  ushort* val   = (ushort*)(ws + 10441600);        // bf16, 3,993,600 el
  ushort* vt    = (ushort*)(ws + 12438400);        // bf16, 4,325,376 el
  ushort* Wcat  = (ushort*)(ws + 14601088);        // bf16, 28,672 el
  float*  bcat  = ws + 14615424;                   // fp32, 320
  ushort* Wf1b  = Wcat + 320*64;
  ushort* Wf2b  = Wcat + 384*64;

  wpack_kernel<<<7, 256, 0, stream>>>(Wq, bq, Wk, bk, Wks, bks,
                                      Wv, bv, Wvs, bvs, Wf1, Wf2, Wcat, bcat);
  prep_kernel<<<NPROJ + NBIAS + NPAD, 256, 0, stream>>>(
      x, Wcat, bcat, proj, vt, Wdi, Wdo, A, AT, biasP);
  attn_kernel<<<dim3(KH*BT, 21), 256, 0, stream>>>(proj, biasP, vt, val);
  ffn_kernel<<<975, 256, 0, stream>>>(val, x, Wf1b, bf1, Wf2b, bf2,
                                      g_ln, b_ln, out);
}

// Round 8
// 198.138 us; speedup vs baseline: 6.9715x; 1.0583x over previous
//
#include <hip/hip_runtime.h>
#include <hip/hip_bf16.h>
#include <math.h>

#define NN 325
#define FD 64
#define KH 4
#define DH 16
#define BT 192
#define NN2 (NN*NN)
#define PST (NN*DH)     // 5200 elems per (proj,head,bt) slice
#define SSTR 340        // attn S row stride (dwords)
#define BSTR 352        // padded bias row stride (floats)
#define VTS  352        // vT row stride (bf16)
#define VSLICE (16*VTS) // vT per-(h,bt) slice
#define HSTR 72         // ffn LDS stride (bf16)
#define NPROJ 975
#define NBIAS ((KH*NN*BSTR + 255)/256)   // 1788
#define NPAD  (KH*BT)                    // 768
#define LOG2E 1.44269504088896f

typedef __attribute__((ext_vector_type(8))) short short8;
typedef __attribute__((ext_vector_type(4))) float f32x4;

union U8 { uint4 u; short8 s; ushort us[8]; };
__device__ inline short8 lds8(const ushort* p){ U8 t; t.u = *(const uint4*)p; return t.s; }
__device__ inline float b2f(ushort v){ return __uint_as_float(((unsigned)v) << 16); }
__device__ inline ushort f2b(float f){
  unsigned u = __float_as_uint(f);
  u += 0x7fff + ((u >> 16) & 1);
  return (ushort)(u >> 16);
}
__device__ inline unsigned pk2(float a, float b){
  union { __hip_bfloat162 h; unsigned u; } t;
  t.h = __float22bfloat162_rn(float2{a, b});
  return t.u;
}
__device__ inline short8 cvt8(const float* p){
  float4 u = ((const float4*)p)[0], v = ((const float4*)p)[1];
  U8 t;
  t.us[0]=f2b(u.x); t.us[1]=f2b(u.y); t.us[2]=f2b(u.z); t.us[3]=f2b(u.w);
  t.us[4]=f2b(v.x); t.us[5]=f2b(v.y); t.us[6]=f2b(v.z); t.us[7]=f2b(v.w);
  return t.s;
}

// ---------------- wpack: W's -> Wcat bf16 [448][64] + bcat ----------------
__global__ __launch_bounds__(256) void wpack_kernel(
    const float* __restrict__ Wq,  const float* __restrict__ bq,
    const float* __restrict__ Wk,  const float* __restrict__ bk,
    const float* __restrict__ Wks, const float* __restrict__ bks,
    const float* __restrict__ Wv,  const float* __restrict__ bv,
    const float* __restrict__ Wvs, const float* __restrict__ bvs,
    const float* __restrict__ Wf1, const float* __restrict__ Wf2,
    ushort* __restrict__ Wcat, float* __restrict__ bcat){
  int blk = blockIdx.x;
  const float* Ws[7] = {Wq, Wk, Wks, Wv, Wvs, Wf1, Wf2};
  const float* bs[5] = {bq, bk, bks, bv, bvs};
  int f = blk * 64 + (threadIdx.x >> 2);
  int c0 = (threadIdx.x & 3) * 8;
  const float* wr = Ws[blk] + (f & 63) * 64;
  unsigned* dst = (unsigned*)Wcat + f * 32 + c0;
  #pragma unroll
  for (int c = 0; c < 8; ++c)
    dst[c] = f2b(wr[2*(c0+c)]) | ((unsigned)f2b(wr[2*(c0+c)+1]) << 16);
  if (blk < 5 && (threadIdx.x & 3) == 0) bcat[f] = bs[blk][f & 63];
}

// ---------------- prep: proj (+V->vt direct) | bias padded | vt pad zero ----------------
__global__ __launch_bounds__(256) void prep_kernel(
    const float* __restrict__ x, const ushort* __restrict__ Wcat,
    const float* __restrict__ bcat, ushort* __restrict__ proj,
    ushort* __restrict__ vt,
    const float* __restrict__ Wdi, const float* __restrict__ Wdo,
    const float* __restrict__ A,   const float* __restrict__ AT,
    float* __restrict__ biasP){
  int bid = blockIdx.x, tid = threadIdx.x;
  if (bid < NPROJ){
    // ---- projections via MFMA (A=W rows, B=x rows) ----
    int lane = tid & 63, wid = tid >> 6;
    int r0 = bid * 64 + wid * 16;
    int m = lane & 15, g = lane >> 4;
    int gr = r0 + m;
    int bt = gr / NN, n = gr - bt * NN;
    const float* xr = x + (size_t)gr * 64 + g * 8;
    short8 xb0 = cvt8(xr);
    short8 xb1 = cvt8(xr + 32);
    for (int ct = 0; ct < 20; ++ct){
      short8 w0 = lds8(Wcat + ((size_t)(ct*16 + m) * 64 + g * 8));
      short8 w1 = lds8(Wcat + ((size_t)(ct*16 + m) * 64 + g * 8 + 32));
      float4 b4 = *(const float4*)(bcat + ct*16 + 4*g);
      f32x4 acc = {b4.x, b4.y, b4.z, b4.w};
      acc = __builtin_amdgcn_mfma_f32_16x16x32_bf16(w0, xb0, acc, 0, 0, 0);
      acc = __builtin_amdgcn_mfma_f32_16x16x32_bf16(w1, xb1, acc, 0, 0, 0);
      if (ct >= 12 && ct < 16){
        // V head (ct-12): write transposed directly to vt[d][n]
        ushort* vs = vt + (size_t)((ct-12)*BT + bt) * VSLICE + n;
        #pragma unroll
        for (int rg = 0; rg < 4; ++rg)
          vs[(size_t)(4*g + rg) * VTS] = f2b(acc[rg]);
      } else {
        // fold 1/sqrt(D) AND log2(e) into Q (softmax runs on exp2)
        float sc = (ct < 4) ? 0.25f * LOG2E : 1.0f;
        uint2 w;
        w.x = pk2(acc[0]*sc, acc[1]*sc);
        w.y = pk2(acc[2]*sc, acc[3]*sc);
        *(uint2*)(proj + ((size_t)ct * BT + bt) * PST + n*16 + 4*g) = w;
      }
    }
  } else if (bid < NPROJ + NBIAS){
    // ---- bias padded [4][325][352] x log2e, pad = -1e30 ----
    int idx = (bid - NPROJ) * 256 + tid;
    if (idx >= KH * NN * BSTR) return;
    int h = idx / (NN * BSTR), rem = idx - h * (NN * BSTR);
    int n = rem / BSTR, m = rem - n * BSTR;
    float s = -1e30f;
    if (m < NN){
      int r = n * NN + m;
      s = 0.f;
      if (h < 2){
        #pragma unroll
        for (int k = 0; k < 3; ++k) s += Wdi[(h*3 + k)*NN2 + r] * A[k*NN2 + r];
      } else {
        int h2 = h - 2;
        #pragma unroll
        for (int k = 0; k < 3; ++k) s += Wdo[(h2*3 + k)*NN2 + r] * AT[k*NN2 + r];
      }
      s *= LOG2E;
    }
    biasP[idx] = s;
  } else {
    // ---- vt pad: zero cols 325..351 for one (h,bt) slice ----
    int slice = bid - NPROJ - NBIAS;
    ushort* vs = vt + (size_t)slice * VSLICE;
    if (tid < 432){
      int d = tid / 27, c = NN + tid % 27;
      vs[(size_t)d * VTS + c] = 0;
    }
  }
}

// ---------------- attention: block per (bhid, qt); all global loads prefetched ----------------
__global__ __launch_bounds__(256, 4) void attn_kernel(
    const ushort* __restrict__ proj, const float* __restrict__ biasP,
    const ushort* __restrict__ vt, ushort* __restrict__ val){
  __shared__ float S[16 * SSTR];       // fp32 scores; P in-place bf16
  __shared__ float part[4][16][16];
  __shared__ float rstat[16][2];
  int bhid = blockIdx.x, qt = blockIdx.y;
  int h = bhid / BT, bt = bhid - h * BT;
  int tid = threadIdx.x, lane = tid & 63, wid = tid >> 6;
  const ushort* qb  = proj + (size_t)((0*KH + h)*BT + bt) * PST;
  const ushort* kb  = proj + (size_t)((1*KH + h)*BT + bt) * PST;
  const ushort* ksb = proj + (size_t)((2*KH + h)*BT + bt) * PST;
  const ushort* vsb = proj + (size_t)((4*KH + h)*BT + bt) * PST;
  const ushort* vtg = vt + (size_t)(h*BT + bt) * VSLICE;

  int m = lane & 15, g = lane >> 4;
  short8 zero = {0,0,0,0,0,0,0,0};

  // ---------- prefetch ALL global data up front ----------
  short8 aq = (g < 2) ? lds8(qb + ((size_t)(qt*16 + m) * 16 + g * 8)) : zero;
  short8 kf[6];
  #pragma unroll
  for (int i = 0; i < 6; ++i){
    int ct = wid + 4*i;
    kf[i] = (ct < 21 && g < 2) ? lds8(kb + ((size_t)(ct*16 + m) * 16 + g * 8)) : zero;
  }
  short8 vf[3];
  #pragma unroll
  for (int i = 0; i < 3; ++i){
    int tt = wid + 4*i;
    vf[i] = (tt < 11) ? lds8(vtg + (size_t)m * VTS + tt*32 + g*8) : zero;
  }
  int r = tid >> 4, c = tid & 15;
  int n = qt * 16 + r;
  int nb = min(n, NN - 1);
  const float* bp = biasP + (size_t)(h*NN + nb) * BSTR;
  float4 b4[6];
  #pragma unroll
  for (int j = 0; j < 6; ++j){
    int m0 = c * 4 + 64 * j;
    b4[j] = (m0 < 336) ? *(const float4*)(bp + m0) : make_float4(0.f,0.f,0.f,0.f);
  }
  float qv  = b2f(qb[(size_t)nb * 16 + c]);
  float kv  = b2f(ksb[(size_t)nb * 16 + c]);
  float vsv = b2f(vsb[(size_t)nb * 16 + c]);

  // ---------- phase 1: S = Q' K^T ----------
  #pragma unroll
  for (int i = 0; i < 6; ++i){
    int ct = wid + 4*i;
    if (ct < 21){
      f32x4 acc = {0.f, 0.f, 0.f, 0.f};
      acc = __builtin_amdgcn_mfma_f32_16x16x32_bf16(aq, kf[i], acc, 0, 0, 0);
      #pragma unroll
      for (int rg = 0; rg < 4; ++rg)
        S[(g*4 + rg)*SSTR + ct*16 + m] = acc[rg];
    }
  }
  __syncthreads();

  // ---------- phase 2: exp2 softmax, pack P in place (single pass) ----------
  {
    float* sr = S + r * SSTR;
    ushort* pr = (ushort*)sr;
    float sum = 0.f;
    #pragma unroll
    for (int j = 0; j < 6; ++j){
      int m0 = c * 4 + 64 * j;
      if (m0 < 336){
        float4 s4 = *(const float4*)(sr + m0);
        float e0 = __builtin_amdgcn_exp2f(s4.x + b4[j].x);
        float e1 = __builtin_amdgcn_exp2f(s4.y + b4[j].y);
        float e2 = __builtin_amdgcn_exp2f(s4.z + b4[j].z);
        float e3 = __builtin_amdgcn_exp2f(s4.w + b4[j].w);
        sum += (e0 + e1) + (e2 + e3);
        uint2 w;
        w.x = pk2(e0, e1);
        w.y = pk2(e2, e3);
        *(uint2*)(pr + m0) = w;
      }
    }
    float dp = qv * kv;
    dp += __shfl_xor(dp, 1, 64); dp += __shfl_xor(dp, 2, 64);
    dp += __shfl_xor(dp, 4, 64); dp += __shfl_xor(dp, 8, 64);
    sum += __shfl_xor(sum, 1, 64); sum += __shfl_xor(sum, 2, 64);
    sum += __shfl_xor(sum, 4, 64); sum += __shfl_xor(sum, 8, 64);
    if (c == 0){
      float esv = __builtin_amdgcn_rcpf(1.f + __builtin_amdgcn_exp2f(-dp));
      float iv  = __builtin_amdgcn_rcpf(esv + sum);
      rstat[r][0] = iv; rstat[r][1] = 1.f - sum * iv;
    }
  }
  __syncthreads();

  // ---------- phase 3: PV from prefetched vT fragments ----------
  {
    const ushort* prow = (const ushort*)S + (size_t)m * (SSTR * 2);
    f32x4 acc = {0.f, 0.f, 0.f, 0.f};
    #pragma unroll
    for (int i = 0; i < 3; ++i){
      int tt = wid + 4*i;
      if (tt < 11){
        short8 ap = (tt == 10 && g >= 2) ? zero : lds8(prow + tt*32 + g*8);
        acc = __builtin_amdgcn_mfma_f32_16x16x32_bf16(ap, vf[i], acc, 0, 0, 0);
      }
    }
    #pragma unroll
    for (int rg = 0; rg < 4; ++rg)
      part[wid][g*4 + rg][m] = acc[rg];
  }
  __syncthreads();

  // ---------- epilogue ----------
  if (n < NN){
    float s = part[0][r][c] + part[1][r][c] + part[2][r][c] + part[3][r][c];
    float res = s * rstat[r][0] + rstat[r][1] * vsv;
    val[((size_t)bt * NN + n) * FD + h * 16 + c] = f2b(res);
  }
}

// ---------------- FFN + residual + LayerNorm (swapped operands, no barrier) ----------------
__global__ __launch_bounds__(256) void ffn_kernel(
    const ushort* __restrict__ val, const float* __restrict__ x,
    const ushort* __restrict__ Wf1b, const float* __restrict__ bf1,
    const ushort* __restrict__ Wf2b, const float* __restrict__ bf2,
    const float* __restrict__ g_ln, const float* __restrict__ b_ln,
    float* __restrict__ out){
  __shared__ ushort hs[4][16 * HSTR];   // wave-private slices
  int tid = threadIdx.x, lane = tid & 63, wid = tid >> 6;
  int m = lane & 15, g = lane >> 4;
  int r0 = blockIdx.x * 64 + wid * 16;
  int row = r0 + m;

  short8 vb0 = lds8(val + ((size_t)row * 64 + g * 8));
  short8 vb1 = lds8(val + ((size_t)row * 64 + g * 8 + 32));

  #pragma unroll
  for (int ct = 0; ct < 4; ++ct){
    short8 w0 = lds8(Wf1b + ((size_t)(ct*16 + m) * 64 + g * 8));
    short8 w1 = lds8(Wf1b + ((size_t)(ct*16 + m) * 64 + g * 8 + 32));
    float4 b4 = *(const float4*)(bf1 + ct*16 + 4*g);
    f32x4 acc = {b4.x, b4.y, b4.z, b4.w};
    acc = __builtin_amdgcn_mfma_f32_16x16x32_bf16(w0, vb0, acc, 0, 0, 0);
    acc = __builtin_amdgcn_mfma_f32_16x16x32_bf16(w1, vb1, acc, 0, 0, 0);
    uint2 w;
    float g0 = 0.5f*acc[0]*(1.f + erff(acc[0]*0.70710678118654752f));
    float g1 = 0.5f*acc[1]*(1.f + erff(acc[1]*0.70710678118654752f));
    float g2 = 0.5f*acc[2]*(1.f + erff(acc[2]*0.70710678118654752f));
    float g3 = 0.5f*acc[3]*(1.f + erff(acc[3]*0.70710678118654752f));
    w.x = pk2(g0, g1); w.y = pk2(g2, g3);
    *(uint2*)&hs[wid][m * HSTR + ct*16 + 4*g] = w;
  }
  asm volatile("s_waitcnt lgkmcnt(0)" ::: "memory");
  short8 h0 = lds8(&hs[wid][m * HSTR + g * 8]);
  short8 h1 = lds8(&hs[wid][m * HSTR + g * 8 + 32]);

  float t[4][4];
  #pragma unroll
  for (int ct = 0; ct < 4; ++ct){
    short8 w0 = lds8(Wf2b + ((size_t)(ct*16 + m) * 64 + g * 8));
    short8 w1 = lds8(Wf2b + ((size_t)(ct*16 + m) * 64 + g * 8 + 32));
    float4 b4 = *(const float4*)(bf2 + ct*16 + 4*g);
    f32x4 acc = {b4.x, b4.y, b4.z, b4.w};
    acc = __builtin_amdgcn_mfma_f32_16x16x32_bf16(w0, h0, acc, 0, 0, 0);
    acc = __builtin_amdgcn_mfma_f32_16x16x32_bf16(w1, h1, acc, 0, 0, 0);
    float4 xr = *(const float4*)(x + (size_t)row * 64 + ct*16 + 4*g);
    t[ct][0] = acc[0] + xr.x; t[ct][1] = acc[1] + xr.y;
    t[ct][2] = acc[2] + xr.z; t[ct][3] = acc[3] + xr.w;
  }
  float s = 0.f;
  #pragma unroll
  for (int ct = 0; ct < 4; ++ct) s += (t[ct][0]+t[ct][1]) + (t[ct][2]+t[ct][3]);
  s += __shfl_xor(s, 16, 64); s += __shfl_xor(s, 32, 64);
  float mu = s * (1.f/64.f);
  float v = 0.f;
  #pragma unroll
  for (int ct = 0; ct < 4; ++ct){
    #pragma unroll
    for (int rg = 0; rg < 4; ++rg){ float d = t[ct][rg] - mu; v += d*d; }
  }
  v += __shfl_xor(v, 16, 64); v += __shfl_xor(v, 32, 64);
  float rs = rsqrtf(v * (1.f/64.f) + 1e-5f);
  #pragma unroll
  for (int ct = 0; ct < 4; ++ct){
    float4 g4 = *(const float4*)(g_ln + ct*16 + 4*g);
    float4 bb = *(const float4*)(b_ln + ct*16 + 4*g);
    float4 o;
    o.x = g4.x*(t[ct][0]-mu)*rs + bb.x;
    o.y = g4.y*(t[ct][1]-mu)*rs + bb.y;
    o.z = g4.z*(t[ct][2]-mu)*rs + bb.z;
    o.w = g4.w*(t[ct][3]-mu)*rs + bb.w;
    *(float4*)(out + (size_t)row * 64 + ct*16 + 4*g) = o;
  }
}

extern "C" void kernel_launch(void* const* d_in, const int* in_sizes, int n_in,
                              void* d_out, int out_size, void* d_ws, size_t ws_size,
                              hipStream_t stream) {
  const float* x    = (const float*)d_in[0];
  const float* A    = (const float*)d_in[1];
  const float* AT   = (const float*)d_in[2];
  const float* Wq   = (const float*)d_in[3];
  const float* bq   = (const float*)d_in[4];
  const float* Wk   = (const float*)d_in[5];
  const float* bk   = (const float*)d_in[6];
  const float* Wks  = (const float*)d_in[7];
  const float* bks  = (const float*)d_in[8];
  const float* Wv   = (const float*)d_in[9];
  const float* bv   = (const float*)d_in[10];
  const float* Wvs  = (const float*)d_in[11];
  const float* bvs  = (const float*)d_in[12];
  const float* Wdi  = (const float*)d_in[13];
  const float* Wdo  = (const float*)d_in[14];
  const float* Wf1  = (const float*)d_in[15];
  const float* bf1  = (const float*)d_in[16];
  const float* Wf2  = (const float*)d_in[17];
  const float* bf2  = (const float*)d_in[18];
  const float* g_ln = (const float*)d_in[19];
  const float* b_ln = (const float*)d_in[20];
  float* out = (float*)d_out;

  float* ws = (float*)d_ws;
  ushort* proj  = (ushort*)ws;                     // bf16, 19,968,000 el (p=3 unused)
  float*  biasP = ws + 9984000;                    // fp32, 457,600
  ushort* val   = (ushort*)(ws + 10441600);        // bf16, 3,993,600 el
  ushort* vt    = (ushort*)(ws + 12438400);        // bf16, 4,325,376 el
  ushort* Wcat  = (ushort*)(ws + 14601088);        // bf16, 28,672 el
  float*  bcat  = ws + 14615424;                   // fp32, 320
  ushort* Wf1b  = Wcat + 320*64;
  ushort* Wf2b  = Wcat + 384*64;

  wpack_kernel<<<7, 256, 0, stream>>>(Wq, bq, Wk, bk, Wks, bks,
                                      Wv, bv, Wvs, bvs, Wf1, Wf2, Wcat, bcat);
  prep_kernel<<<NPROJ + NBIAS + NPAD, 256, 0, stream>>>(
      x, Wcat, bcat, proj, vt, Wdi, Wdo, A, AT, biasP);
  attn_kernel<<<dim3(KH*BT, 21), 256, 0, stream>>>(proj, biasP, vt, val);
  ffn_kernel<<<975, 256, 0, stream>>>(val, x, Wf1b, bf1, Wf2b, bf2,
                                      g_ln, b_ln, out);
}